// Round 13
// baseline (470.077 us; speedup 1.0000x reference)
//
#include <hip/hip_runtime.h>
#include <hip/hip_bf16.h>
#include <math.h>

typedef __attribute__((ext_vector_type(8))) short bf16x8;
typedef __attribute__((ext_vector_type(4))) float f32x4;

__device__ __forceinline__ float eluf(float v){ return v > 0.f ? v : expm1f(v); }
__device__ __forceinline__ float sigf(float v){ return 1.f/(1.f+expf(-v)); }
__device__ __forceinline__ unsigned short f2bf(float f){
  unsigned u = __float_as_uint(f);
  u += 0x7FFFu + ((u >> 16) & 1u);          // round-to-nearest-even
  return (unsigned short)(u >> 16);
}
__device__ __forceinline__ float bf2f(short s){
  return __uint_as_float(((unsigned)(unsigned short)s) << 16);
}

// ---------------- block-wide sum & sumsq reduction ----------------
__device__ __forceinline__ void block_reduce2(float& a, float& b, float* sbuf){
  __syncthreads();
  for (int off = 32; off; off >>= 1){
    a += __shfl_down(a, off);
    b += __shfl_down(b, off);
  }
  int lane = threadIdx.x & 63, w = threadIdx.x >> 6;
  if (lane == 0){ sbuf[2*w] = a; sbuf[2*w+1] = b; }
  __syncthreads();
  if (threadIdx.x == 0){
    int nw = blockDim.x >> 6;
    float sa = 0.f, sb = 0.f;
    for (int i = 0; i < nw; i++){ sa += sbuf[2*i]; sb += sbuf[2*i+1]; }
    sbuf[0] = sa; sbuf[1] = sb;
  }
  __syncthreads();
  a = sbuf[0]; b = sbuf[1];
}

// ---------------- prep helpers ----------------
__device__ __forceinline__ float fold_sum(const float* __restrict__ w, int O, int I,
                                          int o, int i, int pa, int pb, int da, int db){
  float s = 0.f;
  for (int kh = 0; kh < 4; kh++){
    bool inh = (pb==0) ? (db==0 ? (kh==0) : (kh>=1)) : (db==0 ? (kh<=2) : (kh==3));
    if (!inh) continue;
    for (int kw = 0; kw < 4; kw++){
      bool inw = (pa==0) ? (da==0 ? (kw==0) : (kw>=1)) : (da==0 ? (kw<=2) : (kw==3));
      if (!inw) continue;
      s += w[((o*I + i)*4 + kh)*4 + kw];
    }
  }
  return s;
}
__device__ __forceinline__ void fold_elem(const float* __restrict__ w, float* __restrict__ CW,
                                          int O, int I, int l){
  int o = l % O; int q = l / O;
  int da = q & 1, db = (q>>1)&1, pa = (q>>2)&1, pb = (q>>3)&1, i = q>>4;
  CW[(((pb*2+pa)*4 + db*2+da)*I + i)*O + o] = fold_sum(w, O, I, o, i, pa, pb, da, db);
}
__device__ __forceinline__ void cvtc2_elem(const float* __restrict__ w, short* __restrict__ D, int l){
  int i = l & 15, t = (l>>4) & 15, o = l>>8;
  D[l] = (short)f2bf(w[(o*16 + i)*16 + t]);
}
__device__ __forceinline__ void cvtc3_elem(const float* __restrict__ w, short* __restrict__ D, int l){
  int i = l & 31, t = (l>>5) & 15, o = l>>9;
  D[l] = (short)f2bf(w[(o*32 + i)*16 + t]);
}
__device__ __forceinline__ void foldd1_elem(const float* __restrict__ w, short* __restrict__ D, int l){
  int i = l & 63, tap = (l>>6)&3, o = (l>>8)&31, ph = l>>13;
  D[l] = (short)f2bf(fold_sum(w, 32, 64, o, i, ph&1, ph>>1, tap&1, tap>>1));
}
__device__ __forceinline__ void foldd2_elem(const float* __restrict__ w, short* __restrict__ D, int l){
  int i = l & 31, tap = (l>>5)&3, o = (l>>7)&15, ph = l>>11;
  D[l] = (short)f2bf(fold_sum(w, 16, 32, o, i, ph&1, ph>>1, tap&1, tap>>1));
}

// ---------------- combined prep: weight transposes (blocks 0..1199) + small packs ----------------
__global__ __launch_bounds__(256) void prep_combined(
  const float* __restrict__ efc,  short* __restrict__ Defc,
  const float* __restrict__ dfc2, short* __restrict__ Ddfc2,
  const float* __restrict__ outw, short* __restrict__ Dout,
  const float* __restrict__ corew,short* __restrict__ Dcore,
  const float* __restrict__ dfc1, short* __restrict__ Ddfc1,
  const float* __restrict__ renc, short* __restrict__ Drenc,
  const float* __restrict__ ctx,  short* __restrict__ Dctx,
  const float* __restrict__ att1, short* __restrict__ Datt1,
  const float* __restrict__ d3w, float* __restrict__ CWT3,
  const float* __restrict__ c2w, short* __restrict__ BtC2,
  const float* __restrict__ c3w, short* __restrict__ BtC3,
  const float* __restrict__ d1w, short* __restrict__ BD1,
  const float* __restrict__ d2w, short* __restrict__ BD2,
  const float* __restrict__ state, short* __restrict__ SBF,
  short* __restrict__ TOTb)
{
  int bx = blockIdx.x;
  if (bx >= 1200){
    const int F3=256, P2=F3+8192, P3=P2+32768, P4=P3+32768, P5=P4+8192,
              ST=P5+98304, TOTAL=ST+4608;
    for (int l = (bx-1200)*256 + threadIdx.x; l < TOTAL; l += 256*256){
      if (l < F3)      fold_elem(d3w, CWT3, 1, 16, l);
      else if (l < P2) cvtc2_elem(c2w, BtC2, l - F3);
      else if (l < P3) cvtc3_elem(c3w, BtC3, l - P2);
      else if (l < P4) foldd1_elem(d1w, BD1, l - P3);
      else if (l < P5) foldd2_elem(d2w, BD2, l - P4);
      else if (l < ST){
        int q = l - P5;             // state -> bf16 [384][256], zero pad
        int n = q >> 8, k = q & 255;
        SBF[q] = (k < 250) ? (short)f2bf(state[n*250 + k]) : (short)0;
      } else {
        int q = l - ST;             // zero TOT pad cols: 250..255, 506..511
        int row = q / 12, cc = q % 12;
        int col = cc < 6 ? 250 + cc : 506 + (cc - 6);
        TOTb[row*1024 + col] = 0;
      }
    }
    return;
  }
  // transpose-convert W[K][N] -> D[Npad][Kp] bf16, zero-padded rows/cols
  const float* W; short* D; int K, N, Np, Kp, base, mode = 0;
  if      (bx < 512) { W=efc;  D=Defc;  K=4096; N=512;  Np=512;  Kp=4096; base=0;    }
  else if (bx < 1024){ W=dfc2; D=Ddfc2; K=512;  N=4096; Np=4096; Kp=512;  base=512;  }
  else if (bx < 1088){ W=outw; D=Dout;  K=1012; N=250;  Np=256;  Kp=1024; base=1024; mode=2; }
  else if (bx < 1120){ W=corew;D=Dcore; K=500;  N=250;  Np=256;  Kp=512;  base=1088; mode=1; }
  else if (bx < 1152){ W=dfc1; D=Ddfc1; K=250;  N=512;  Np=512;  Kp=256;  base=1120; }
  else if (bx < 1168){ W=renc; D=Drenc; K=250;  N=250;  Np=256;  Kp=256;  base=1152; }
  else if (bx < 1184){ W=ctx;  D=Dctx;  K=250;  N=250;  Np=256;  Kp=256;  base=1168; }
  else               { W=att1; D=Datt1; K=250;  N=100;  Np=256;  Kp=256;  base=1184; }
  int t = bx - base;
  int tpr = Kp >> 6;
  int tk = t % tpr, tn = t / tpr;
  __shared__ short tile[64][65];
  int c = threadIdx.x & 63, r4 = threadIdx.x >> 6;
  int n0 = tn*64, k0 = tk*64;
  #pragma unroll 4
  for (int p = 0; p < 16; p++){
    int r = r4*16 + p;
    int k = k0 + r, n = n0 + c;
    int ksrc = k; bool valid;
    if (mode == 0) valid = (k < K);
    else if (mode == 1){ valid = (k < 250) || (k >= 256 && k < 506); ksrc = k < 256 ? k : k - 6; }
    else { valid = (k < 250) || (k >= 256 && k < 506) || (k >= 512);
           ksrc = k < 256 ? k : (k < 512 ? k - 6 : k - 12); }
    float v = (valid && n < N) ? W[(size_t)ksrc*N + n] : 0.f;
    tile[c][r] = (short)f2bf(v);
  }
  __syncthreads();
  #pragma unroll 4
  for (int p = 0; p < 16; p++){
    int nn = r4*16 + p;
    int n = n0 + nn;
    if (n < Np) D[(size_t)n*Kp + k0 + c] = tile[nn][c];
  }
}

// ---------------- MFMA bf16 split-K GEMM, bf16 A (for efc, dfc2) ----------------
__global__ __launch_bounds__(256) void gemm_mfma(
    const short* __restrict__ Ab, const short* __restrict__ Bt,
    float* __restrict__ P, int M, int N, int Kp, int Kc)
{
  __shared__ __align__(16) short As[64*32];
  __shared__ __align__(16) short Bs[64*32];
  int tid = threadIdx.x;
  int bm = blockIdx.y*64, bn = blockIdx.x*64;
  int kb = blockIdx.z * Kc;
  int kend = kb + Kc;

  int r = tid >> 2, c = tid & 3;
  const short* Arow = Ab + (size_t)(bm + r)*Kp;
  int gn = bn + r;
  bool bval = gn < N;
  const short* Brow = Bt + (size_t)gn*Kp;

  uint4 hA, hB;
  auto load_regs = [&](int k0){
    hA = *(const uint4*)&Arow[k0 + c*8];
    hB = bval ? *(const uint4*)&Brow[k0 + c*8] : make_uint4(0,0,0,0);
  };
  auto write_lds = [&](){
    *(uint4*)&As[r*32 + c*8] = hA;
    *(uint4*)&Bs[r*32 + c*8] = hB;
  };

  int wave = tid >> 6;
  int ln = tid & 15, quad = (tid >> 4) & 3;
  int wr = (wave >> 1) * 32, wc = (wave & 1) * 32;

  f32x4 zero = {0.f, 0.f, 0.f, 0.f};
  f32x4 acc[2][2] = {{zero, zero}, {zero, zero}};

  load_regs(kb);
  write_lds();
  __syncthreads();
  for (int k0 = kb; k0 < kend; k0 += 32){
    int nxt = k0 + 32;
    if (nxt < kend) load_regs(nxt);
    bf16x8 a0 = *(const bf16x8*)&As[(wr +      ln)*32 + quad*8];
    bf16x8 a1 = *(const bf16x8*)&As[(wr + 16 + ln)*32 + quad*8];
    bf16x8 b0 = *(const bf16x8*)&Bs[(wc +      ln)*32 + quad*8];
    bf16x8 b1 = *(const bf16x8*)&Bs[(wc + 16 + ln)*32 + quad*8];
    acc[0][0] = __builtin_amdgcn_mfma_f32_16x16x32_bf16(a0, b0, acc[0][0], 0, 0, 0);
    acc[0][1] = __builtin_amdgcn_mfma_f32_16x16x32_bf16(a0, b1, acc[0][1], 0, 0, 0);
    acc[1][0] = __builtin_amdgcn_mfma_f32_16x16x32_bf16(a1, b0, acc[1][0], 0, 0, 0);
    acc[1][1] = __builtin_amdgcn_mfma_f32_16x16x32_bf16(a1, b1, acc[1][1], 0, 0, 0);
    __syncthreads();
    if (nxt < kend){ write_lds(); __syncthreads(); }
  }

  float* Pout = P + (size_t)blockIdx.z*M*N;
  #pragma unroll
  for (int t = 0; t < 2; t++)
    #pragma unroll
    for (int u = 0; u < 2; u++)
      #pragma unroll
      for (int j = 0; j < 4; j++){
        int row = bm + wr + t*16 + quad*4 + j;
        int col = bn + wc + u*16 + ln;
        if (col < N) Pout[(size_t)row*N + col] = acc[t][u][j];
      }
}

// ---------------- fused single-pass GEMM + row LN + act ----------------
// Block computes MR rows x NC cols, full K. act: 1 relu, 2 elu, 3 tanh, 4 NS(XR+sout).
// Tb nonnull => core pair-gather A from padded TOT.
template<int MR, int NC>
__global__ __launch_bounds__(256) void gemm_ln_f(
    const short* __restrict__ Ab, const short* __restrict__ Tb,
    const short* __restrict__ Bt, const float* __restrict__ bias,
    void* __restrict__ outp, float* __restrict__ sout,
    int N, int Kp, int os, int act, int obf)
{
  constexpr int MT = MR/16;
  constexpr int NU = NC/64;            // u-tiles per wave
  constexpr int APT = (MR*8 + 255)/256;
  constexpr int BPT = NC*4/256;        // uint4 loads per thread (full 32-k coverage)
  __shared__ __align__(16) short As[MR*32];
  __shared__ __align__(16) short Bs[NC*32];
  __shared__ float ls_s[4][MR], ls_q[4][MR];
  int tid = threadIdx.x;
  int bm = blockIdx.x * MR;
  int wave = tid>>6, ln = tid&15, quad = (tid>>4)&3;

  uint2 hA[APT]; uint4 hB[BPT];
  auto load_regs = [&](int k0){
    #pragma unroll
    for (int i = 0; i < APT; i++){
      int idx = tid + i*256;
      if (idx < MR*8){
        int r = idx>>3, ch = idx&7;
        int kk = k0 + ch*4;
        const short* src;
        if (Tb){
          int gr = bm + r;
          int jj2 = gr % 7, fi2 = gr / 7;
          int ii = fi2 & 7, j2 = fi2 >> 3;
          int jidx = jj2 < ii ? jj2 : jj2 + 1;
          const short* base = (kk & 256) ? (Tb + (size_t)(j2*8+jidx)*1024)
                                         : (Tb + (size_t)fi2*1024);
          src = base + (kk & 255);
        } else {
          src = Ab + (size_t)(bm + r)*Kp + kk;
        }
        hA[i] = *(const uint2*)src;
      }
    }
    #pragma unroll
    for (int i = 0; i < BPT; i++){
      int idx = tid + i*256;
      int n = idx>>2, ch = idx&3;
      hB[i] = *(const uint4*)&Bt[(size_t)n*Kp + k0 + ch*8];
    }
  };
  auto write_lds = [&](){
    #pragma unroll
    for (int i = 0; i < APT; i++){
      int idx = tid + i*256;
      if (idx < MR*8){
        int r = idx>>3, ch = idx&7;
        *(uint2*)&As[r*32 + ch*4] = hA[i];
      }
    }
    #pragma unroll
    for (int i = 0; i < BPT; i++){
      int idx = tid + i*256;
      int n = idx>>2, ch = idx&3;
      *(uint4*)&Bs[n*32 + ch*8] = hB[i];
    }
  };

  f32x4 z = {0.f,0.f,0.f,0.f};
  f32x4 acc[MT][NU];
  #pragma unroll
  for (int mt = 0; mt < MT; mt++)
    #pragma unroll
    for (int u = 0; u < NU; u++) acc[mt][u] = z;

  load_regs(0);
  write_lds();
  __syncthreads();
  for (int k0 = 0; k0 < Kp; k0 += 32){
    int nxt = k0 + 32;
    if (nxt < Kp) load_regs(nxt);
    bf16x8 a[MT];
    #pragma unroll
    for (int mt = 0; mt < MT; mt++)
      a[mt] = *(const bf16x8*)&As[(mt*16 + ln)*32 + quad*8];
    #pragma unroll
    for (int u = 0; u < NU; u++){
      bf16x8 b = *(const bf16x8*)&Bs[(wave*NU*16 + u*16 + ln)*32 + quad*8];
      #pragma unroll
      for (int mt = 0; mt < MT; mt++)
        acc[mt][u] = __builtin_amdgcn_mfma_f32_16x16x32_bf16(a[mt], b, acc[mt][u], 0,0,0);
    }
    __syncthreads();
    if (nxt < Kp){ write_lds(); __syncthreads(); }
  }

  // bias + per-row partial sums
  float sl[MT][4], ql[MT][4];
  #pragma unroll
  for (int mt = 0; mt < MT; mt++)
    #pragma unroll
    for (int j = 0; j < 4; j++){
      float ss = 0.f, qq = 0.f;
      #pragma unroll
      for (int u = 0; u < NU; u++){
        int col = wave*NU*16 + u*16 + ln;
        float bv = (col < N) ? bias[col] : 0.f;
        float v = acc[mt][u][j] + bv;
        acc[mt][u][j] = v;
        ss += v; qq += v*v;
      }
      sl[mt][j] = ss; ql[mt][j] = qq;
    }
  #pragma unroll
  for (int off = 8; off; off >>= 1)
    #pragma unroll
    for (int mt = 0; mt < MT; mt++)
      #pragma unroll
      for (int j = 0; j < 4; j++){
        sl[mt][j] += __shfl_down(sl[mt][j], off, 16);
        ql[mt][j] += __shfl_down(ql[mt][j], off, 16);
      }
  if (ln == 0){
    #pragma unroll
    for (int mt = 0; mt < MT; mt++)
      #pragma unroll
      for (int j = 0; j < 4; j++){
        int r = mt*16 + quad*4 + j;
        ls_s[wave][r] = sl[mt][j];
        ls_q[wave][r] = ql[mt][j];
      }
  }
  __syncthreads();
  float invN = 1.f / (float)N;
  #pragma unroll
  for (int mt = 0; mt < MT; mt++)
    #pragma unroll
    for (int j = 0; j < 4; j++){
      int r = mt*16 + quad*4 + j;
      int row = bm + r;
      float S = ls_s[0][r] + ls_s[1][r] + ls_s[2][r] + ls_s[3][r];
      float Q = ls_q[0][r] + ls_q[1][r] + ls_q[2][r] + ls_q[3][r];
      float m = S*invN;
      float rinv = rsqrtf(Q*invN - m*m + 1e-5f);
      #pragma unroll
      for (int u = 0; u < NU; u++){
        int col = wave*NU*16 + u*16 + ln;
        if (col >= N) continue;
        float v = acc[mt][u][j];
        float lnv = (v - m)*rinv;
        if (act == 4){
          ((short*)outp)[(size_t)row*os + col] = f2bf(sigf(lnv));
          sout[(size_t)row*250 + col] = sigf(v);
        } else {
          float w = lnv;
          if (act == 1) w = fmaxf(w, 0.f);
          else if (act == 2) w = eluf(w);
          else if (act == 3) w = tanhf(w);
          if (obf) ((short*)outp)[(size_t)row*os + col] = f2bf(w);
          else     ((float*)outp)[(size_t)row*os + col] = w;
        }
      }
    }
}

// ---------------- fused: out = act(LN_last(sum_ks P + bias)); obf: write bf16 ----------------
__global__ __launch_bounds__(256) void reduce_ln(
    const float* __restrict__ Pp, const float* __restrict__ bias,
    void* __restrict__ outp, int M, int N, int KS, int os, int act, int obf)
{
  __shared__ float rowbuf[4096];
  __shared__ float sbuf[16];
  int row = blockIdx.x;
  size_t MN = (size_t)M*N;
  float s = 0.f, s2 = 0.f;
  for (int c = threadIdx.x; c < N; c += 256){
    float v = bias[c];
    for (int ks = 0; ks < KS; ks++) v += Pp[ks*MN + (size_t)row*N + c];
    rowbuf[c] = v; s += v; s2 += v*v;
  }
  block_reduce2(s, s2, sbuf);
  float m = s / N;
  float r = rsqrtf(s2/N - m*m + 1e-5f);
  for (int c = threadIdx.x; c < N; c += 256){
    float v = (rowbuf[c]-m)*r;
    if (act == 1) v = fmaxf(v, 0.f);
    else if (act == 2) v = eluf(v);
    else if (act == 3) v = tanhf(v);
    if (obf) ((short*)outp)[(size_t)row*os + c] = f2bf(v);
    else     ((float*)outp)[(size_t)row*os + c] = v;
  }
}

// ---------------- effect: att2 dot + weighted sum (wave per jj) ----------------
__global__ __launch_bounds__(448) void effect_kernel(
    const float* __restrict__ A1f, const short* __restrict__ X1b,
    const float* __restrict__ w2, const float* __restrict__ b2,
    short* __restrict__ tot)
{
  __shared__ float att_s[7];
  int fi = blockIdx.x, tid = threadIdx.x;
  int jj = tid >> 6, lane = tid & 63;
  int row = fi*7 + jj;
  float d = 0.f;
  #pragma unroll
  for (int t = 0; t < 2; t++){
    int c = lane + t*64;
    if (c < 100) d += A1f[(size_t)row*128 + c]*w2[c];
  }
  #pragma unroll
  for (int off = 32; off; off >>= 1) d += __shfl_down(d, off);
  if (lane == 0) att_s[jj] = sigf(d + b2[0]);
  __syncthreads();
  for (int h = tid; h < 250; h += 448){
    float sum = 0.f;
    #pragma unroll
    for (int q = 0; q < 7; q++)
      sum += bf2f(X1b[((size_t)fi*7 + q)*256 + h])*att_s[q];
    tot[(size_t)fi*1024 + 256 + h] = f2bf(sum);
  }
}

// ---------------- enc_conv1: x(n,64,64) -> FINAL bf16 elu(LN) (n,32,32,16) ----------------
__global__ __launch_bounds__(256) void enc_conv1_ig(
    const float* __restrict__ x, const float* __restrict__ w, const float* __restrict__ bias,
    short* __restrict__ outp)
{
  __shared__ __align__(16) float in_t[66*68];
  __shared__ short rawb[16384];
  __shared__ float sbuf[16];
  int n = blockIdx.x, tid = threadIdx.x;
  for (int l = tid; l < 66*68; l += 256) in_t[l] = 0.f;
  __syncthreads();
  const float* xin = x + (size_t)n*4096;
  for (int l4 = tid; l4 < 1024; l4 += 256){
    float4 v = *(const float4*)&xin[l4*4];
    int aa = (l4*4) >> 6, bb = (l4*4) & 63;
    float* dst = &in_t[(aa+1)*68 + bb + 1];
    dst[0]=v.x; dst[1]=v.y; dst[2]=v.z; dst[3]=v.w;
  }
  int o = tid & 15;
  float wr[16];
  #pragma unroll
  for (int t = 0; t < 16; t++) wr[t] = w[o*16 + t];
  float bv = bias[o];
  __syncthreads();
  float s = 0.f, s2 = 0.f;
  for (int r = 0; r < 64; r++){
    int idx = tid + (r<<8);
    int bq = (idx>>4)&31, aq = idx>>9;
    int a0 = 2*aq, b0 = 2*bq;
    float acc = bv;
    #pragma unroll
    for (int kw = 0; kw < 4; kw++){
      const float* row = &in_t[(a0+kw)*68 + b0];
      float2 p0 = *(const float2*)&row[0];
      float2 p1 = *(const float2*)&row[2];
      acc += p0.x*wr[0*4+kw] + p0.y*wr[1*4+kw] + p1.x*wr[2*4+kw] + p1.y*wr[3*4+kw];
    }
    rawb[idx] = f2bf(acc);
    s += acc; s2 += acc*acc;
  }
  block_reduce2(s, s2, sbuf);
  float m = s*(1.f/16384.f);
  float rs = rsqrtf(s2*(1.f/16384.f) - m*m + 1e-5f);
  short* op = outp + (size_t)n*16384;
  for (int l = tid; l < 16384; l += 256){
    float v = bf2f(rawb[l]);
    op[l] = f2bf(eluf((v-m)*rs));
  }
}

// ---------------- enc_conv2 MFMA: final bf16 in -> final bf16 elu(LN) out ----------------
__global__ __launch_bounds__(256) void enc_conv2_mfma(
    const short* __restrict__ in, const short* __restrict__ Bt, const float* __restrict__ bias,
    short* __restrict__ outp)
{
  __shared__ __align__(16) short in_t[34*34*16];
  __shared__ float sbuf[16];
  int n = blockIdx.x, tid = threadIdx.x;
  for (int l = tid; l < 34*34*16/4; l += 256) ((unsigned long long*)in_t)[l] = 0ull;
  __syncthreads();
  const short* ip = in + (size_t)n*16384;
  for (int l = tid; l < 4096; l += 256){
    int i4 = l & 3, bb = (l>>2) & 31, aa = l>>7;
    *(uint2*)&in_t[((aa+1)*34 + (bb+1))*16 + i4*4] = *(const uint2*)&ip[aa*512 + bb*16 + i4*4];
  }
  int wave = tid>>6, ln = tid&15, quad = (tid>>4)&3;
  bf16x8 bfr[2][8];
  #pragma unroll
  for (int nt = 0; nt < 2; nt++){
    const short* Brow = Bt + (nt*16 + ln)*256;
    #pragma unroll
    for (int ks = 0; ks < 8; ks++)
      bfr[nt][ks] = *(const bf16x8*)&Brow[ks*32 + quad*8];
  }
  __syncthreads();
  f32x4 z = {0.f,0.f,0.f,0.f};
  f32x4 acc[2][4] = {{z,z,z,z},{z,z,z,z}};
  int tapq = quad>>1, io = (quad&1)*8;
  #pragma unroll
  for (int ks = 0; ks < 8; ks++){
    int t = 2*ks + tapq;
    int kh = t>>2, kw = t&3;
    #pragma unroll
    for (int mt = 0; mt < 4; mt++){
      int p = (wave*4 + mt)*16 + ln;
      int oa = p>>4, ob = p&15;
      bf16x8 a = *(const bf16x8*)&in_t[((2*oa+kw)*34 + (2*ob+kh))*16 + io];
      acc[0][mt] = __builtin_amdgcn_mfma_f32_16x16x32_bf16(a, bfr[0][ks], acc[0][mt],0,0,0);
      acc[1][mt] = __builtin_amdgcn_mfma_f32_16x16x32_bf16(a, bfr[1][ks], acc[1][mt],0,0,0);
    }
  }
  float s = 0.f, s2 = 0.f;
  #pragma unroll
  for (int nt = 0; nt < 2; nt++){
    float bz = bias[nt*16 + ln];
    #pragma unroll
    for (int mt = 0; mt < 4; mt++)
      #pragma unroll
      for (int j = 0; j < 4; j++){
        float v = acc[nt][mt][j] + bz;
        acc[nt][mt][j] = v; s += v; s2 += v*v;
      }
  }
  block_reduce2(s, s2, sbuf);
  float m = s*(1.f/8192.f);
  float rs = rsqrtf(s2*(1.f/8192.f) - m*m + 1e-5f);
  short* op = outp + (size_t)n*8192;
  #pragma unroll
  for (int nt = 0; nt < 2; nt++){
    int o = nt*16 + ln;
    #pragma unroll
    for (int mt = 0; mt < 4; mt++)
      #pragma unroll
      for (int j = 0; j < 4; j++){
        int p = (wave*4 + mt)*16 + quad*4 + j;
        int oa = p>>4, ob = p&15;
        op[oa*512 + ob*32 + o] = f2bf(eluf((acc[nt][mt][j]-m)*rs));
      }
  }
}

// ---------------- enc_conv3 MFMA: final bf16 in -> final bf16 elu(LN) out ----------------
__global__ __launch_bounds__(256) void enc_conv3_mfma(
    const short* __restrict__ in, const short* __restrict__ Bt, const float* __restrict__ bias,
    short* __restrict__ outp)
{
  __shared__ __align__(16) short in_t[18*18*32];
  __shared__ float sbuf[16];
  int n = blockIdx.x, tid = threadIdx.x;
  for (int l = tid; l < 18*18*32/4; l += 256) ((unsigned long long*)in_t)[l] = 0ull;
  __syncthreads();
  const short* ip = in + (size_t)n*8192;
  for (int l = tid; l < 2048; l += 256){
    int i4 = l & 7, bb = (l>>3)&15, aa = l>>7;
    *(uint2*)&in_t[((aa+1)*18 + (bb+1))*32 + i4*4] = *(const uint2*)&ip[aa*512 + bb*32 + i4*4];
  }
  int wave = tid>>6, ln = tid&15, quad = (tid>>4)&3;
  int o = wave*16 + ln;
  bf16x8 bfr[16];
  {
    const short* Brow = Bt + o*512;
    #pragma unroll
    for (int ks = 0; ks < 16; ks++)
      bfr[ks] = *(const bf16x8*)&Brow[ks*32 + quad*8];
  }
  __syncthreads();
  f32x4 z = {0.f,0.f,0.f,0.f};
  f32x4 acc[4] = {z,z,z,z};
  #pragma unroll
  for (int ks = 0; ks < 16; ks++){
    int kh = ks>>2, kw = ks&3;
    #pragma unroll
    for (int mt = 0; mt < 4; mt++){
      int p = mt*16 + ln;
      int oa = p>>3, ob = p&7;
      bf16x8 a = *(const bf16x8*)&in_t[((2*oa+kw)*18 + (2*ob+kh))*32 + quad*8];
      acc[mt] = __builtin_amdgcn_mfma_f32_16x16x32_bf16(a, bfr[ks], acc[mt],0,0,0);
    }
  }
  float s = 0.f, s2 = 0.f;
  float bz = bias[o];
  #pragma unroll
  for (int mt = 0; mt < 4; mt++)
    #pragma unroll
    for (int j = 0; j < 4; j++){
      float v = acc[mt][j] + bz;
      acc[mt][j] = v; s += v; s2 += v*v;
    }
  block_reduce2(s, s2, sbuf);
  float m = s*(1.f/4096.f);
  float rs = rsqrtf(s2*(1.f/4096.f) - m*m + 1e-5f);
  short* op = outp + (size_t)n*4096;
  #pragma unroll
  for (int mt = 0; mt < 4; mt++)
    #pragma unroll
    for (int j = 0; j < 4; j++){
      int p = mt*16 + quad*4 + j;
      int oa = p>>3, ob = p&7;
      op[oa*512 + ob*64 + o] = f2bf(eluf((acc[mt][j]-m)*rs));
    }
}

// ---------------- dec_conv1 MFMA: final bf16 in -> final bf16 relu(LN) out ----------------
__global__ __launch_bounds__(256) void dec_conv1_mfma(
    const short* __restrict__ in, const short* __restrict__ Bd, const float* __restrict__ bias,
    short* __restrict__ outp)
{
  __shared__ __align__(16) short in_t[10*10*64];
  __shared__ float sbuf[16];
  int n = blockIdx.x, tid = threadIdx.x;
  for (int l = tid; l < 10*10*64/4; l += 256) ((unsigned long long*)in_t)[l] = 0ull;
  __syncthreads();
  const short* ip = in + (size_t)n*4096;
  for (int l = tid; l < 1024; l += 256){
    int i4 = l & 15, sb = (l>>4)&7, sa = l>>7;
    *(uint2*)&in_t[((sa+1)*10 + (sb+1))*64 + i4*4] = *(const uint2*)&ip[sa*512 + sb*64 + i4*4];
  }
  int wave = tid>>6, ln = tid&15, quad = (tid>>4)&3;
  int pa = wave & 1, pb = wave >> 1;
  bf16x8 bfr[2][8];
  #pragma unroll
  for (int nt = 0; nt < 2; nt++){
    const short* Brow = Bd + (wave*32 + nt*16 + ln)*256;
    #pragma unroll
    for (int ks = 0; ks < 8; ks++)
      bfr[nt][ks] = *(const bf16x8*)&Brow[ks*32 + quad*8];
  }
  __syncthreads();
  f32x4 z = {0.f,0.f,0.f,0.f};
  f32x4 acc[2][4] = {{z,z,z,z},{z,z,z,z}};
  #pragma unroll
  for (int ks = 0; ks < 8; ks++){
    int tap = ks>>1, ibase = (ks&1)*32 + quad*8;
    int da = tap & 1, db = tap >> 1;
    #pragma unroll
    for (int mt = 0; mt < 4; mt++){
      int p = mt*16 + ln;
      int ta = p>>3, tb = p&7;
      bf16x8 a = *(const bf16x8*)&in_t[((ta+da+pa)*10 + (tb+db+pb))*64 + ibase];
      acc[0][mt] = __builtin_amdgcn_mfma_f32_16x16x32_bf16(a, bfr[0][ks], acc[0][mt],0,0,0);
      acc[1][mt] = __builtin_amdgcn_mfma_f32_16x16x32_bf16(a, bfr[1][ks], acc[1][mt],0,0,0);
    }
  }
  float s = 0.f, s2 = 0.f;
  #pragma unroll
  for (int nt = 0; nt < 2; nt++){
    float bz = bias[nt*16 + ln];
    #pragma unroll
    for (int mt = 0; mt < 4; mt++)
      #pragma unroll
      for (int j = 0; j < 4; j++){
        float v = acc[nt][mt][j] + bz;
        acc[nt][mt][j] = v; s += v; s2 += v*v;
      }
  }
  block_reduce2(s, s2, sbuf);
  float m = s*(1.f/8192.f);
  float rs = rsqrtf(s2*(1.f/8192.f) - m*m + 1e-5f);
  short* op = outp + (size_t)n*8192;
  #pragma unroll
  for (int nt = 0; nt < 2; nt++){
    int o = nt*16 + ln;
    #pragma unroll
    for (int mt = 0; mt < 4; mt++)
      #pragma unroll
      for (int j = 0; j < 4; j++){
        int p = mt*16 + quad*4 + j;
        int ta = p>>3, tb = p&7;
        op[(2*ta+pa)*512 + (2*tb+pb)*32 + o] = f2bf(fmaxf((acc[nt][mt][j]-m)*rs, 0.f));
      }
  }
}

// ---------------- dec_conv2 MFMA: final bf16 in -> final bf16 relu(LN) out ----------------
__global__ __launch_bounds__(256) void dec_conv2_mfma(
    const short* __restrict__ in, const short* __restrict__ Bd, const float* __restrict__ bias,
    short* __restrict__ outp)
{
  __shared__ __align__(16) short in_t[18*18*32];
  __shared__ float sbuf[16];
  int n = blockIdx.x, tid = threadIdx.x;
  for (int l = tid; l < 18*18*32/4; l += 256) ((unsigned long long*)in_t)[l] = 0ull;
  __syncthreads();
  const short* ip = in + (size_t)n*8192;
  for (int l = tid; l < 2048; l += 256){
    int i4 = l & 7, sb = (l>>3)&15, sa = l>>7;
    *(uint2*)&in_t[((sa+1)*18 + (sb+1))*32 + i4*4] = *(const uint2*)&ip[sa*512 + sb*32 + i4*4];
  }
  int wave = tid>>6, ln = tid&15, quad = (tid>>4)&3;
  int pa = wave & 1, pb = wave >> 1;
  bf16x8 bfr[4];
  {
    const short* Brow = Bd + (wave*16 + ln)*128;
    #pragma unroll
    for (int ks = 0; ks < 4; ks++)
      bfr[ks] = *(const bf16x8*)&Brow[ks*32 + quad*8];
  }
  __syncthreads();
  f32x4 z = {0.f,0.f,0.f,0.f};
  f32x4 acc[16] = {z,z,z,z,z,z,z,z,z,z,z,z,z,z,z,z};
  #pragma unroll
  for (int ks = 0; ks < 4; ks++){
    int da = ks & 1, db = ks >> 1;
    #pragma unroll
    for (int mt = 0; mt < 16; mt++){
      int p = mt*16 + ln;
      int ta = p>>4, tb = p&15;
      bf16x8 a = *(const bf16x8*)&in_t[((ta+da+pa)*18 + (tb+db+pb))*32 + quad*8];
      acc[mt] = __builtin_amdgcn_mfma_f32_16x16x32_bf16(a, bfr[ks], acc[mt],0,0,0);
    }
  }
  float s = 0.f, s2 = 0.f;
  float bz = bias[ln];
  #pragma unroll
  for (int mt = 0; mt < 16; mt++)
    #pragma unroll
    for (int j = 0; j < 4; j++){
      float v = acc[mt][j] + bz;
      acc[mt][j] = v; s += v; s2 += v*v;
    }
  block_reduce2(s, s2, sbuf);
  float m = s*(1.f/16384.f);
  float rs = rsqrtf(s2*(1.f/16384.f) - m*m + 1e-5f);
  short* op = outp + (size_t)n*16384;
  #pragma unroll
  for (int mt = 0; mt < 16; mt++)
    #pragma unroll
    for (int j = 0; j < 4; j++){
      int p = mt*16 + quad*4 + j;
      int ta = p>>4, tb = p&15;
      op[(2*ta+pa)*512 + (2*tb+pb)*16 + ln] = f2bf(fmaxf((acc[mt][j]-m)*rs, 0.f));
    }
}

// ---------------- dec_conv3 (final bf16 in) ----------------
__global__ __launch_bounds__(256) void dec_conv3_ig(
    const short* __restrict__ in, const float* __restrict__ CWT, const float* __restrict__ bias,
    float* __restrict__ outp)
{
  __shared__ __align__(16) float in_t[9792];   // [sa34][sb18][i16]
  __shared__ __align__(16) float wl[256];
  int bx = blockIdx.x;
  int n = bx >> 1, b0 = (bx & 1) * 32, tb0 = b0 >> 1;
  int tid = threadIdx.x;
  const short* ip = in + (size_t)n*16384;
  for (int l = tid; l < 9792; l += 256){
    int i = l & 15, sb = (l >> 4) % 18, sap = l / 288;
    int sa = sap - 1, sbg = tb0 - 1 + sb;
    float v = 0.f;
    if ((unsigned)sa < 32u && (unsigned)sbg < 32u)
      v = bf2f(ip[sa*512 + sbg*16 + i]);
    in_t[(sap*18 + sb)*16 + i] = v;
  }
  for (int l = tid; l < 256; l += 256) wl[l] = CWT[l];
  __syncthreads();
  float bv = bias[0];
  int bl = tid & 31, ath = tid >> 5;
  int b = b0 + bl;
  int tb = b >> 1, pb = b & 1;
  float* op = outp + (size_t)n*4096;
  #pragma unroll
  for (int j = 0; j < 8; j++){
    int a = ath*8 + j;
    int ta = a >> 1, pa = a & 1;
    float4 s4 = make_float4(0.f,0.f,0.f,0.f);
    #pragma unroll
    for (int db = 0; db < 2; db++){
      int sb = tb + db + (pb ? 0 : -1);
      int sbl = sb - (tb0 - 1);
      #pragma unroll
      for (int da = 0; da < 2; da++){
        int sa = ta + da + (pa ? 0 : -1);
        int sap = sa + 1;
        const float4* A4 = (const float4*)&in_t[(sap*18 + sbl)*16];
        const float4* B4 = (const float4*)&wl[((pb*2+pa)*4 + db*2+da)*16];
        #pragma unroll
        for (int q = 0; q < 4; q++){
          float4 av = A4[q], bw = B4[q];
          s4.x += av.x*bw.x; s4.y += av.y*bw.y;
          s4.z += av.z*bw.z; s4.w += av.w*bw.w;
        }
      }
    }
    op[a*64 + b] = sigf(bv + s4.x + s4.y + s4.z + s4.w);
  }
}

extern "C" void kernel_launch(void* const* d_in, const int* in_sizes, int n_in,
                              void* d_out, int out_size, void* d_ws, size_t ws_size,
                              hipStream_t stream) {
  const float* x      = (const float*)d_in[0];
  const float* state  = (const float*)d_in[1];
  const float* c1w    = (const float*)d_in[2];
  const float* c1b    = (const float*)d_in[3];
  const float* c2w    = (const float*)d_in[4];
  const float* c2b    = (const float*)d_in[5];
  const float* c3w    = (const float*)d_in[6];
  const float* c3b    = (const float*)d_in[7];
  const float* efc_w  = (const float*)d_in[8];
  const float* efc_b  = (const float*)d_in[9];
  const float* renc_w = (const float*)d_in[10];
  const float* renc_b = (const float*)d_in[11];
  const float* core_w = (const float*)d_in[12];
  const float* core_b = (const float*)d_in[13];
  const float* ctx_w  = (const float*)d_in[14];
  const float* ctx_b  = (const float*)d_in[15];
  const float* att1_w = (const float*)d_in[16];
  const float* att1_b = (const float*)d_in[17];
  const float* att2_w = (const float*)d_in[18];
  const float* att2_b = (const float*)d_in[19];
  const float* out_w  = (const float*)d_in[20];
  const float* out_b  = (const float*)d_in[21];
  const float* dfc1_w = (const float*)d_in[22];
  const float* dfc1_b = (const float*)d_in[23];
  const float* dfc2_w = (const float*)d_in[24];
  const float* dfc2_b = (const float*)d_in[25];
  const float* d1w    = (const float*)d_in[26];
  const float* d1b    = (const float*)d_in[27];
  const float* d2w    = (const float*)d_in[28];
  const float* d2b    = (const float*)d_in[29];
  const float* d3w    = (const float*)d_in[30];
  const float* d3b    = (const float*)d_in[31];

  float* wsf = (float*)d_ws;
  size_t o = 0;
  float* PB   = wsf + o; o += (size_t)1600*1024;    // split-K partials (efc, dfc2)
  float* A1f  = wsf + o; o += (size_t)2688*128;     // att1 LN+tanh out
  float* CWT3 = wsf + o; o += 256;
  // bf16 buffers (sizes in shorts; offsets in floats)
  short* E1b  = (short*)(wsf + o); o += (size_t)384*16384/2;   // enc1 final; later dec2 final
  short* E2b  = (short*)(wsf + o); o += (size_t)384*8192/2;    // enc2 final; later dec1 final
  short* E3b  = (short*)(wsf + o); o += (size_t)384*4096/2;    // enc3 final; later G2 final
  short* TOTb = (short*)(wsf + o); o += (size_t)384*1024/2;    // [s1|pad|eff|pad|h]
  short* C1b  = (short*)(wsf + o); o += (size_t)2688*256/2;
  short* X1b  = (short*)(wsf + o); o += (size_t)2688*256/2;
  short* XRb  = (short*)(wsf + o); o += (size_t)384*256/2;
  short* G1b  = (short*)(wsf + o); o += (size_t)384*512/2;
  short* SBF  = (short*)(wsf + o); o += (size_t)384*256/2;
  short* BtC2 = (short*)(wsf + o); o += 8192/2;
  short* BtC3 = (short*)(wsf + o); o += 32768/2;
  short* BD1  = (short*)(wsf + o); o += 32768/2;
  short* BD2  = (short*)(wsf + o); o += 8192/2;
  short* BT_efc  = (short*)(wsf + o); o += 2097152/2;
  short* BT_renc = (short*)(wsf + o); o += 65536/2;     // 256 x 256
  short* BT_core = (short*)(wsf + o); o += 131072/2;    // 256 x 512
  short* BT_ctx  = (short*)(wsf + o); o += 65536/2;     // 256 x 256
  short* BT_att1 = (short*)(wsf + o); o += 65536/2;     // 256 x 256
  short* BT_out  = (short*)(wsf + o); o += 262144/2;    // 256 x 1024
  short* BT_dfc1 = (short*)(wsf + o); o += 131072/2;    // 512 x 256
  short* BT_dfc2 = (short*)(wsf + o); o += 2097152/2;
  short* D1b = E2b;
  short* D2b = E1b;
  short* G2b = E3b;

  float* xout = (float*)d_out;
  float* sout = xout + (size_t)384*4096;

  // one prep kernel: padded weight transposes + folds + state cvt + TOT pad zero
  prep_combined<<<1456, 256, 0, stream>>>(
      efc_w, BT_efc, dfc2_w, BT_dfc2, out_w, BT_out, core_w, BT_core,
      dfc1_w, BT_dfc1, renc_w, BT_renc, ctx_w, BT_ctx, att1_w, BT_att1,
      d3w, CWT3, c2w, BtC2, c3w, BtC3, d1w, BD1, d2w, BD2, state, SBF, TOTb);

  // encoder
  enc_conv1_ig<<<384, 256, 0, stream>>>(x, c1w, c1b, E1b);
  enc_conv2_mfma<<<384, 256, 0, stream>>>(E1b, BtC2, c2b, E2b);
  enc_conv3_mfma<<<384, 256, 0, stream>>>(E2b, BtC3, c3b, E3b);
  gemm_mfma<<<dim3(8,6,8), 256, 0, stream>>>(E3b, BT_efc, PB, 384, 512, 4096, 512);
  reduce_ln<<<384, 256, 0, stream>>>(PB, efc_b, TOTb+512, 384, 512, 8, 1024, 2, 1);

  // state path (fused GEMM+LN)
  gemm_ln_f<32,256><<<12, 256, 0, stream>>>(SBF, nullptr, BT_renc, renc_b,
                                            TOTb, nullptr, 250, 256, 1024, 1, 1);
  gemm_ln_f<32,256><<<84, 256, 0, stream>>>(nullptr, TOTb, BT_core, core_b,
                                            C1b, nullptr, 250, 512, 256, 1, 1);
  gemm_ln_f<32,256><<<84, 256, 0, stream>>>(C1b, nullptr, BT_ctx, ctx_b,
                                            X1b, nullptr, 250, 256, 256, 1, 1);
  gemm_ln_f<32,256><<<84, 256, 0, stream>>>(C1b, nullptr, BT_att1, att1_b,
                                            A1f, nullptr, 100, 256, 128, 3, 0);
  effect_kernel<<<384, 448, 0, stream>>>(A1f, X1b, att2_w, att2_b, TOTb);

  // combine (fused GEMM + NS epilogue)
  gemm_ln_f<32,256><<<12, 256, 0, stream>>>(TOTb, nullptr, BT_out, out_b,
                                            XRb, sout, 250, 1024, 256, 4, 1);

  // decoder FC
  gemm_ln_f<16,512><<<24, 256, 0, stream>>>(XRb, nullptr, BT_dfc1, dfc1_b,
                                            G1b, nullptr, 512, 256, 512, 1, 1);
  gemm_mfma<<<dim3(64,6,1), 256, 0, stream>>>(G1b, BT_dfc2, PB, 384, 4096, 512, 512);
  reduce_ln<<<384, 256, 0, stream>>>(PB, dfc2_b, G2b, 384, 4096, 1, 4096, 1, 1);

  // decoder convs
  dec_conv1_mfma<<<384, 256, 0, stream>>>(G2b, BD1, d1b, D1b);
  dec_conv2_mfma<<<384, 256, 0, stream>>>(D1b, BD2, d2b, D2b);
  dec_conv3_ig<<<768, 256, 0, stream>>>(D2b, CWT3, d3b, xout);

  (void)in_sizes; (void)n_in; (void)out_size; (void)ws_size;
}

// Round 14
// 334.535 us; speedup vs baseline: 1.4052x; 1.4052x over previous
//
#include <hip/hip_runtime.h>
#include <hip/hip_bf16.h>
#include <math.h>

typedef __attribute__((ext_vector_type(8))) short bf16x8;
typedef __attribute__((ext_vector_type(4))) float f32x4;

__device__ __forceinline__ float eluf(float v){ return v > 0.f ? v : expm1f(v); }
__device__ __forceinline__ float sigf(float v){ return 1.f/(1.f+expf(-v)); }
__device__ __forceinline__ unsigned short f2bf(float f){
  unsigned u = __float_as_uint(f);
  u += 0x7FFFu + ((u >> 16) & 1u);          // round-to-nearest-even
  return (unsigned short)(u >> 16);
}
__device__ __forceinline__ float bf2f(short s){
  return __uint_as_float(((unsigned)(unsigned short)s) << 16);
}

// ---------------- block-wide sum & sumsq reduction ----------------
__device__ __forceinline__ void block_reduce2(float& a, float& b, float* sbuf){
  __syncthreads();
  for (int off = 32; off; off >>= 1){
    a += __shfl_down(a, off);
    b += __shfl_down(b, off);
  }
  int lane = threadIdx.x & 63, w = threadIdx.x >> 6;
  if (lane == 0){ sbuf[2*w] = a; sbuf[2*w+1] = b; }
  __syncthreads();
  if (threadIdx.x == 0){
    int nw = blockDim.x >> 6;
    float sa = 0.f, sb = 0.f;
    for (int i = 0; i < nw; i++){ sa += sbuf[2*i]; sb += sbuf[2*i+1]; }
    sbuf[0] = sa; sbuf[1] = sb;
  }
  __syncthreads();
  a = sbuf[0]; b = sbuf[1];
}

// ---------------- prep helpers ----------------
__device__ __forceinline__ float fold_sum(const float* __restrict__ w, int O, int I,
                                          int o, int i, int pa, int pb, int da, int db){
  float s = 0.f;
  for (int kh = 0; kh < 4; kh++){
    bool inh = (pb==0) ? (db==0 ? (kh==0) : (kh>=1)) : (db==0 ? (kh<=2) : (kh==3));
    if (!inh) continue;
    for (int kw = 0; kw < 4; kw++){
      bool inw = (pa==0) ? (da==0 ? (kw==0) : (kw>=1)) : (da==0 ? (kw<=2) : (kw==3));
      if (!inw) continue;
      s += w[((o*I + i)*4 + kh)*4 + kw];
    }
  }
  return s;
}
__device__ __forceinline__ void fold_elem(const float* __restrict__ w, float* __restrict__ CW,
                                          int O, int I, int l){
  int o = l % O; int q = l / O;
  int da = q & 1, db = (q>>1)&1, pa = (q>>2)&1, pb = (q>>3)&1, i = q>>4;
  CW[(((pb*2+pa)*4 + db*2+da)*I + i)*O + o] = fold_sum(w, O, I, o, i, pa, pb, da, db);
}
__device__ __forceinline__ void cvtc2_elem(const float* __restrict__ w, short* __restrict__ D, int l){
  int i = l & 15, t = (l>>4) & 15, o = l>>8;        // k = t*16 + i
  D[l] = (short)f2bf(w[(o*16 + i)*16 + t]);
}
__device__ __forceinline__ void cvtc3_elem(const float* __restrict__ w, short* __restrict__ D, int l){
  int i = l & 31, t = (l>>5) & 15, o = l>>9;        // k = t*32 + i
  D[l] = (short)f2bf(w[(o*32 + i)*16 + t]);
}
__device__ __forceinline__ void foldd1_elem(const float* __restrict__ w, short* __restrict__ D, int l){
  int i = l & 63, tap = (l>>6)&3, o = (l>>8)&31, ph = l>>13;
  D[l] = (short)f2bf(fold_sum(w, 32, 64, o, i, ph&1, ph>>1, tap&1, tap>>1));
}
__device__ __forceinline__ void foldd2_elem(const float* __restrict__ w, short* __restrict__ D, int l){
  int i = l & 31, tap = (l>>5)&3, o = (l>>7)&15, ph = l>>11;
  D[l] = (short)f2bf(fold_sum(w, 16, 32, o, i, ph&1, ph>>1, tap&1, tap>>1));
}

// ---------------- combined prep: weight transposes (blocks 0..1191) + small packs ----------------
__global__ __launch_bounds__(256) void prep_combined(
  const float* __restrict__ efc,  short* __restrict__ Defc,
  const float* __restrict__ dfc2, short* __restrict__ Ddfc2,
  const float* __restrict__ outw, short* __restrict__ Dout,
  const float* __restrict__ corew,short* __restrict__ Dcore,
  const float* __restrict__ dfc1, short* __restrict__ Ddfc1,
  const float* __restrict__ renc, short* __restrict__ Drenc,
  const float* __restrict__ ctx,  short* __restrict__ Dctx,
  const float* __restrict__ att1, short* __restrict__ Datt1,
  const float* __restrict__ d3w, float* __restrict__ CWT3,
  const float* __restrict__ c2w, short* __restrict__ BtC2,
  const float* __restrict__ c3w, short* __restrict__ BtC3,
  const float* __restrict__ d1w, short* __restrict__ BD1,
  const float* __restrict__ d2w, short* __restrict__ BD2,
  const float* __restrict__ state, short* __restrict__ SBF,
  short* __restrict__ TOTb)
{
  int bx = blockIdx.x;
  if (bx >= 1192){
    const int F3=256, P2=F3+8192, P3=P2+32768, P4=P3+32768, P5=P4+8192,
              ST=P5+98304, TOTAL=ST+4608;
    for (int l = (bx-1192)*256 + threadIdx.x; l < TOTAL; l += 256*256){
      if (l < F3)      fold_elem(d3w, CWT3, 1, 16, l);
      else if (l < P2) cvtc2_elem(c2w, BtC2, l - F3);
      else if (l < P3) cvtc3_elem(c3w, BtC3, l - P2);
      else if (l < P4) foldd1_elem(d1w, BD1, l - P3);
      else if (l < P5) foldd2_elem(d2w, BD2, l - P4);
      else if (l < ST){
        int q = l - P5;             // state -> bf16 [384][256], zero pad
        int n = q >> 8, k = q & 255;
        SBF[q] = (k < 250) ? (short)f2bf(state[n*250 + k]) : (short)0;
      } else {
        int q = l - ST;             // zero TOT pad cols: 250..255, 506..511
        int row = q / 12, cc = q % 12;
        int col = cc < 6 ? 250 + cc : 506 + (cc - 6);
        TOTb[row*1024 + col] = 0;
      }
    }
    return;
  }
  const float* W; short* D; int K, N, Kp, base, mode = 0;
  if      (bx < 512) { W=efc;  D=Defc;  K=4096; N=512;  Kp=4096; base=0;    }
  else if (bx < 1024){ W=dfc2; D=Ddfc2; K=512;  N=4096; Kp=512;  base=512;  }
  else if (bx < 1088){ W=outw; D=Dout;  K=1012; N=250;  Kp=1024; base=1024; mode=2; }
  else if (bx < 1120){ W=corew;D=Dcore; K=500;  N=250;  Kp=512;  base=1088; mode=1; }
  else if (bx < 1152){ W=dfc1; D=Ddfc1; K=250;  N=512;  Kp=256;  base=1120; }
  else if (bx < 1168){ W=renc; D=Drenc; K=250;  N=250;  Kp=256;  base=1152; }
  else if (bx < 1184){ W=ctx;  D=Dctx;  K=250;  N=250;  Kp=256;  base=1168; }
  else               { W=att1; D=Datt1; K=250;  N=100;  Kp=256;  base=1184; }
  int t = bx - base;
  int tpr = Kp >> 6;
  int tk = t % tpr, tn = t / tpr;
  __shared__ short tile[64][65];
  int c = threadIdx.x & 63, r4 = threadIdx.x >> 6;
  int n0 = tn*64, k0 = tk*64;
  #pragma unroll 4
  for (int p = 0; p < 16; p++){
    int r = r4*16 + p;
    int k = k0 + r, n = n0 + c;
    int ksrc = k; bool valid;
    if (mode == 0) valid = (k < K);
    else if (mode == 1){ valid = (k < 250) || (k >= 256 && k < 506); ksrc = k < 256 ? k : k - 6; }
    else { valid = (k < 250) || (k >= 256 && k < 506) || (k >= 512);
           ksrc = k < 256 ? k : (k < 512 ? k - 6 : k - 12); }
    float v = (valid && n < N) ? W[(size_t)ksrc*N + n] : 0.f;
    tile[c][r] = (short)f2bf(v);
  }
  __syncthreads();
  #pragma unroll 4
  for (int p = 0; p < 16; p++){
    int nn = r4*16 + p;
    int n = n0 + nn;
    if (n < N) D[(size_t)n*Kp + k0 + c] = tile[nn][c];
  }
}

// ---------------- MFMA bf16 split-K GEMM, bf16 A ----------------
__global__ __launch_bounds__(256) void gemm_mfma(
    const short* __restrict__ Ab, const short* __restrict__ Bt,
    float* __restrict__ P, int M, int N, int Kp, int Kc)
{
  __shared__ __align__(16) short As[64*32];
  __shared__ __align__(16) short Bs[64*32];
  int tid = threadIdx.x;
  int bm = blockIdx.y*64, bn = blockIdx.x*64;
  int kb = blockIdx.z * Kc;
  int kend = kb + Kc;

  int r = tid >> 2, c = tid & 3;
  const short* Arow = Ab + (size_t)(bm + r)*Kp;
  int gn = bn + r;
  bool bval = gn < N;
  const short* Brow = Bt + (size_t)gn*Kp;

  uint4 hA, hB;
  auto load_regs = [&](int k0){
    hA = *(const uint4*)&Arow[k0 + c*8];
    hB = bval ? *(const uint4*)&Brow[k0 + c*8] : make_uint4(0,0,0,0);
  };
  auto write_lds = [&](){
    *(uint4*)&As[r*32 + c*8] = hA;
    *(uint4*)&Bs[r*32 + c*8] = hB;
  };

  int wave = tid >> 6;
  int ln = tid & 15, quad = (tid >> 4) & 3;
  int wr = (wave >> 1) * 32, wc = (wave & 1) * 32;

  f32x4 zero = {0.f, 0.f, 0.f, 0.f};
  f32x4 acc[2][2] = {{zero, zero}, {zero, zero}};

  load_regs(kb);
  write_lds();
  __syncthreads();
  for (int k0 = kb; k0 < kend; k0 += 32){
    int nxt = k0 + 32;
    if (nxt < kend) load_regs(nxt);
    bf16x8 a0 = *(const bf16x8*)&As[(wr +      ln)*32 + quad*8];
    bf16x8 a1 = *(const bf16x8*)&As[(wr + 16 + ln)*32 + quad*8];
    bf16x8 b0 = *(const bf16x8*)&Bs[(wc +      ln)*32 + quad*8];
    bf16x8 b1 = *(const bf16x8*)&Bs[(wc + 16 + ln)*32 + quad*8];
    acc[0][0] = __builtin_amdgcn_mfma_f32_16x16x32_bf16(a0, b0, acc[0][0], 0, 0, 0);
    acc[0][1] = __builtin_amdgcn_mfma_f32_16x16x32_bf16(a0, b1, acc[0][1], 0, 0, 0);
    acc[1][0] = __builtin_amdgcn_mfma_f32_16x16x32_bf16(a1, b0, acc[1][0], 0, 0, 0);
    acc[1][1] = __builtin_amdgcn_mfma_f32_16x16x32_bf16(a1, b1, acc[1][1], 0, 0, 0);
    __syncthreads();
    if (nxt < kend){ write_lds(); __syncthreads(); }
  }

  float* Pout = P + (size_t)blockIdx.z*M*N;
  #pragma unroll
  for (int t = 0; t < 2; t++)
    #pragma unroll
    for (int u = 0; u < 2; u++)
      #pragma unroll
      for (int j = 0; j < 4; j++){
        int row = bm + wr + t*16 + quad*4 + j;
        int col = bn + wc + u*16 + ln;
        if (col < N) Pout[(size_t)row*N + col] = acc[t][u][j];
      }
}

// ---------------- core GEMM: A gathered from padded TOT (pair fusion) ----------------
__global__ __launch_bounds__(256) void gemm_core_mfma(
    const short* __restrict__ Tb, const short* __restrict__ Bt,
    float* __restrict__ P, int M, int N, int Kc)
{
  __shared__ __align__(16) short As[64*32];
  __shared__ __align__(16) short Bs[64*32];
  int tid = threadIdx.x;
  int bm = blockIdx.y*64, bn = blockIdx.x*64;
  int kb = blockIdx.z * Kc;
  int kend = kb + Kc;

  int r = tid >> 2, c = tid & 3;
  int gr = bm + r;
  int jj2 = gr % 7, fi2 = gr / 7;
  int ii = fi2 & 7, j2 = fi2 >> 3;
  int jidx = jj2 < ii ? jj2 : jj2 + 1;
  const short* own = Tb + (size_t)fi2*1024;
  const short* oth = Tb + (size_t)(j2*8 + jidx)*1024;
  int gn = bn + r;
  bool bval = gn < N;
  const short* Brow = Bt + (size_t)gn*512;

  uint4 hA, hB;
  auto load_regs = [&](int k0){
    int kk = k0 + c*8;
    const short* src = (kk & 256) ? oth : own;
    hA = *(const uint4*)&src[kk & 255];
    hB = bval ? *(const uint4*)&Brow[kk] : make_uint4(0,0,0,0);
  };
  auto write_lds = [&](){
    *(uint4*)&As[r*32 + c*8] = hA;
    *(uint4*)&Bs[r*32 + c*8] = hB;
  };

  int wave = tid >> 6;
  int ln = tid & 15, quad = (tid >> 4) & 3;
  int wr = (wave >> 1) * 32, wc = (wave & 1) * 32;

  f32x4 zero = {0.f, 0.f, 0.f, 0.f};
  f32x4 acc[2][2] = {{zero, zero}, {zero, zero}};

  load_regs(kb);
  write_lds();
  __syncthreads();
  for (int k0 = kb; k0 < kend; k0 += 32){
    int nxt = k0 + 32;
    if (nxt < kend) load_regs(nxt);
    bf16x8 a0 = *(const bf16x8*)&As[(wr +      ln)*32 + quad*8];
    bf16x8 a1 = *(const bf16x8*)&As[(wr + 16 + ln)*32 + quad*8];
    bf16x8 b0 = *(const bf16x8*)&Bs[(wc +      ln)*32 + quad*8];
    bf16x8 b1 = *(const bf16x8*)&Bs[(wc + 16 + ln)*32 + quad*8];
    acc[0][0] = __builtin_amdgcn_mfma_f32_16x16x32_bf16(a0, b0, acc[0][0], 0, 0, 0);
    acc[0][1] = __builtin_amdgcn_mfma_f32_16x16x32_bf16(a0, b1, acc[0][1], 0, 0, 0);
    acc[1][0] = __builtin_amdgcn_mfma_f32_16x16x32_bf16(a1, b0, acc[1][0], 0, 0, 0);
    acc[1][1] = __builtin_amdgcn_mfma_f32_16x16x32_bf16(a1, b1, acc[1][1], 0, 0, 0);
    __syncthreads();
    if (nxt < kend){ write_lds(); __syncthreads(); }
  }

  float* Pout = P + (size_t)blockIdx.z*M*N;
  #pragma unroll
  for (int t = 0; t < 2; t++)
    #pragma unroll
    for (int u = 0; u < 2; u++)
      #pragma unroll
      for (int j = 0; j < 4; j++){
        int row = bm + wr + t*16 + quad*4 + j;
        int col = bn + wc + u*16 + ln;
        if (col < N) Pout[(size_t)row*N + col] = acc[t][u][j];
      }
}

// ---------------- fused: out = act(LN_last(sum_ks P + bias)); obf: write bf16 ----------------
__global__ __launch_bounds__(256) void reduce_ln(
    const float* __restrict__ Pp, const float* __restrict__ bias,
    void* __restrict__ outp, int M, int N, int KS, int os, int act, int obf)
{
  __shared__ float rowbuf[4096];
  __shared__ float sbuf[16];
  int row = blockIdx.x;
  size_t MN = (size_t)M*N;
  float s = 0.f, s2 = 0.f;
  for (int c = threadIdx.x; c < N; c += 256){
    float v = bias[c];
    for (int ks = 0; ks < KS; ks++) v += Pp[ks*MN + (size_t)row*N + c];
    rowbuf[c] = v; s += v; s2 += v*v;
  }
  block_reduce2(s, s2, sbuf);
  float m = s / N;
  float r = rsqrtf(s2/N - m*m + 1e-5f);
  for (int c = threadIdx.x; c < N; c += 256){
    float v = (rowbuf[c]-m)*r;
    if (act == 1) v = fmaxf(v, 0.f);
    else if (act == 2) v = eluf(v);
    else if (act == 3) v = tanhf(v);
    if (obf) ((short*)outp)[(size_t)row*os + c] = f2bf(v);
    else     ((float*)outp)[(size_t)row*os + c] = v;
  }
}

// ---------------- fused NS: XR bf16, state_out fp32 ----------------
__global__ __launch_bounds__(256) void reduce_ns(
    const float* __restrict__ Pp, const float* __restrict__ bias,
    short* __restrict__ XRb, float* __restrict__ so, int M, int N, int KS)
{
  __shared__ float rowbuf[256];
  __shared__ float sbuf[16];
  int row = blockIdx.x;
  size_t MN = (size_t)M*N;
  float s = 0.f, s2 = 0.f;
  for (int c = threadIdx.x; c < N; c += 256){
    float v = bias[c];
    for (int ks = 0; ks < KS; ks++) v += Pp[ks*MN + (size_t)row*N + c];
    rowbuf[c] = v; s += v; s2 += v*v;
  }
  block_reduce2(s, s2, sbuf);
  float m = s / N;
  float r = rsqrtf(s2/N - m*m + 1e-5f);
  for (int c = threadIdx.x; c < N; c += 256){
    float v = rowbuf[c];
    XRb[(size_t)row*256 + c] = f2bf(sigf((v-m)*r));
    so[(size_t)row*N + c] = sigf(v);
  }
}

// ---------------- ctx/att1 LN + att2 + effect, wave-parallel (7 waves) ----------------
__global__ __launch_bounds__(448) void ctx_att_effect(
    const float* __restrict__ Pc, const float* __restrict__ ctx_b,
    const float* __restrict__ Pa, const float* __restrict__ att1_b,
    const float* __restrict__ w2, const float* __restrict__ b2,
    short* __restrict__ tot)
{
  __shared__ float ctxs[7][250];
  __shared__ float att_s[7];
  int fi = blockIdx.x, tid = threadIdx.x;
  int jj = tid >> 6, lane = tid & 63;
  const size_t MN = (size_t)2688*250, MN2 = (size_t)2688*100;
  int row = fi*7 + jj;
  // ctx: LN + relu
  float vv[4];
  float s = 0.f, s2 = 0.f;
  #pragma unroll
  for (int t = 0; t < 4; t++){
    int c = lane + t*64;
    float v = 0.f;
    if (c < 250) v = ctx_b[c] + Pc[(size_t)row*250 + c] + Pc[MN + (size_t)row*250 + c];
    vv[t] = v; s += v; s2 += v*v;
  }
  #pragma unroll
  for (int off = 32; off; off >>= 1){ s += __shfl_down(s, off); s2 += __shfl_down(s2, off); }
  s = __shfl(s, 0); s2 = __shfl(s2, 0);
  float m = s*(1.f/250.f);
  float r = rsqrtf(s2*(1.f/250.f) - m*m + 1e-5f);
  #pragma unroll
  for (int t = 0; t < 4; t++){
    int c = lane + t*64;
    if (c < 250) ctxs[jj][c] = fmaxf((vv[t]-m)*r, 0.f);
  }
  // att1: LN + tanh + dot(w2) + sigmoid
  float va[2];
  s = 0.f; s2 = 0.f;
  #pragma unroll
  for (int t = 0; t < 2; t++){
    int c = lane + t*64;
    float v = 0.f;
    if (c < 100){
      v = att1_b[c];
      #pragma unroll
      for (int ks = 0; ks < 4; ks++) v += Pa[ks*MN2 + (size_t)row*100 + c];
    }
    va[t] = v; s += v; s2 += v*v;
  }
  #pragma unroll
  for (int off = 32; off; off >>= 1){ s += __shfl_down(s, off); s2 += __shfl_down(s2, off); }
  s = __shfl(s, 0); s2 = __shfl(s2, 0);
  m = s*0.01f;
  r = rsqrtf(s2*0.01f - m*m + 1e-5f);
  float d = 0.f;
  #pragma unroll
  for (int t = 0; t < 2; t++){
    int c = lane + t*64;
    if (c < 100) d += tanhf((va[t]-m)*r)*w2[c];
  }
  #pragma unroll
  for (int off = 32; off; off >>= 1) d += __shfl_down(d, off);
  if (lane == 0) att_s[jj] = sigf(d + b2[0]);
  __syncthreads();
  for (int h = tid; h < 250; h += 448){
    float sum = 0.f;
    #pragma unroll
    for (int q = 0; q < 7; q++) sum += ctxs[q][h]*att_s[q];
    tot[(size_t)fi*1024 + 256 + h] = f2bf(sum);
  }
}

// ---------------- enc_conv1: x(n,64,64) -> FINAL bf16 elu(LN) (n,32,32,16) ----------------
__global__ __launch_bounds__(256) void enc_conv1_ig(
    const float* __restrict__ x, const float* __restrict__ w, const float* __restrict__ bias,
    short* __restrict__ outp)
{
  __shared__ __align__(16) float in_t[66*68];
  __shared__ short rawb[16384];
  __shared__ float sbuf[16];
  int n = blockIdx.x, tid = threadIdx.x;
  for (int l = tid; l < 66*68; l += 256) in_t[l] = 0.f;
  __syncthreads();
  const float* xin = x + (size_t)n*4096;
  for (int l4 = tid; l4 < 1024; l4 += 256){
    float4 v = *(const float4*)&xin[l4*4];
    int aa = (l4*4) >> 6, bb = (l4*4) & 63;
    float* dst = &in_t[(aa+1)*68 + bb + 1];
    dst[0]=v.x; dst[1]=v.y; dst[2]=v.z; dst[3]=v.w;
  }
  int o = tid & 15;
  float wr[16];
  #pragma unroll
  for (int t = 0; t < 16; t++) wr[t] = w[o*16 + t];
  float bv = bias[o];
  __syncthreads();
  float s = 0.f, s2 = 0.f;
  for (int r = 0; r < 64; r++){
    int idx = tid + (r<<8);
    int bq = (idx>>4)&31, aq = idx>>9;
    int a0 = 2*aq, b0 = 2*bq;
    float acc = bv;
    #pragma unroll
    for (int kw = 0; kw < 4; kw++){
      const float* row = &in_t[(a0+kw)*68 + b0];
      float2 p0 = *(const float2*)&row[0];
      float2 p1 = *(const float2*)&row[2];
      acc += p0.x*wr[0*4+kw] + p0.y*wr[1*4+kw] + p1.x*wr[2*4+kw] + p1.y*wr[3*4+kw];
    }
    rawb[idx] = f2bf(acc);
    s += acc; s2 += acc*acc;
  }
  block_reduce2(s, s2, sbuf);
  float m = s*(1.f/16384.f);
  float rs = rsqrtf(s2*(1.f/16384.f) - m*m + 1e-5f);
  short* op = outp + (size_t)n*16384;
  for (int l = tid; l < 16384; l += 256){
    float v = bf2f(rawb[l]);
    op[l] = f2bf(eluf((v-m)*rs));
  }
}

// ---------------- enc_conv2 MFMA: final bf16 in -> final bf16 elu(LN) out ----------------
__global__ __launch_bounds__(256) void enc_conv2_mfma(
    const short* __restrict__ in, const short* __restrict__ Bt, const float* __restrict__ bias,
    short* __restrict__ outp)
{
  __shared__ __align__(16) short in_t[34*34*16];
  __shared__ float sbuf[16];
  int n = blockIdx.x, tid = threadIdx.x;
  for (int l = tid; l < 34*34*16/4; l += 256) ((unsigned long long*)in_t)[l] = 0ull;
  __syncthreads();
  const short* ip = in + (size_t)n*16384;
  for (int l = tid; l < 4096; l += 256){
    int i4 = l & 3, bb = (l>>2) & 31, aa = l>>7;
    *(uint2*)&in_t[((aa+1)*34 + (bb+1))*16 + i4*4] = *(const uint2*)&ip[aa*512 + bb*16 + i4*4];
  }
  int wave = tid>>6, ln = tid&15, quad = (tid>>4)&3;
  bf16x8 bfr[2][8];
  #pragma unroll
  for (int nt = 0; nt < 2; nt++){
    const short* Brow = Bt + (nt*16 + ln)*256;
    #pragma unroll
    for (int ks = 0; ks < 8; ks++)
      bfr[nt][ks] = *(const bf16x8*)&Brow[ks*32 + quad*8];
  }
  __syncthreads();
  f32x4 z = {0.f,0.f,0.f,0.f};
  f32x4 acc[2][4] = {{z,z,z,z},{z,z,z,z}};
  int tapq = quad>>1, io = (quad&1)*8;
  #pragma unroll
  for (int ks = 0; ks < 8; ks++){
    int t = 2*ks + tapq;
    int kh = t>>2, kw = t&3;
    #pragma unroll
    for (int mt = 0; mt < 4; mt++){
      int p = (wave*4 + mt)*16 + ln;
      int oa = p>>4, ob = p&15;
      bf16x8 a = *(const bf16x8*)&in_t[((2*oa+kw)*34 + (2*ob+kh))*16 + io];
      acc[0][mt] = __builtin_amdgcn_mfma_f32_16x16x32_bf16(a, bfr[0][ks], acc[0][mt],0,0,0);
      acc[1][mt] = __builtin_amdgcn_mfma_f32_16x16x32_bf16(a, bfr[1][ks], acc[1][mt],0,0,0);
    }
  }
  float s = 0.f, s2 = 0.f;
  #pragma unroll
  for (int nt = 0; nt < 2; nt++){
    float bz = bias[nt*16 + ln];
    #pragma unroll
    for (int mt = 0; mt < 4; mt++)
      #pragma unroll
      for (int j = 0; j < 4; j++){
        float v = acc[nt][mt][j] + bz;
        acc[nt][mt][j] = v; s += v; s2 += v*v;
      }
  }
  block_reduce2(s, s2, sbuf);
  float m = s*(1.f/8192.f);
  float rs = rsqrtf(s2*(1.f/8192.f) - m*m + 1e-5f);
  short* op = outp + (size_t)n*8192;
  #pragma unroll
  for (int nt = 0; nt < 2; nt++){
    int o = nt*16 + ln;
    #pragma unroll
    for (int mt = 0; mt < 4; mt++)
      #pragma unroll
      for (int j = 0; j < 4; j++){
        int p = (wave*4 + mt)*16 + quad*4 + j;
        int oa = p>>4, ob = p&15;
        op[oa*512 + ob*32 + o] = f2bf(eluf((acc[nt][mt][j]-m)*rs));
      }
  }
}

// ---------------- enc_conv3 MFMA: final bf16 in -> final bf16 elu(LN) out ----------------
__global__ __launch_bounds__(256) void enc_conv3_mfma(
    const short* __restrict__ in, const short* __restrict__ Bt, const float* __restrict__ bias,
    short* __restrict__ outp)
{
  __shared__ __align__(16) short in_t[18*18*32];
  __shared__ float sbuf[16];
  int n = blockIdx.x, tid = threadIdx.x;
  for (int l = tid; l < 18*18*32/4; l += 256) ((unsigned long long*)in_t)[l] = 0ull;
  __syncthreads();
  const short* ip = in + (size_t)n*8192;
  for (int l = tid; l < 2048; l += 256){
    int i4 = l & 7, bb = (l>>3)&15, aa = l>>7;
    *(uint2*)&in_t[((aa+1)*18 + (bb+1))*32 + i4*4] = *(const uint2*)&ip[aa*512 + bb*32 + i4*4];
  }
  int wave = tid>>6, ln = tid&15, quad = (tid>>4)&3;
  int o = wave*16 + ln;
  bf16x8 bfr[16];
  {
    const short* Brow = Bt + o*512;
    #pragma unroll
    for (int ks = 0; ks < 16; ks++)
      bfr[ks] = *(const bf16x8*)&Brow[ks*32 + quad*8];
  }
  __syncthreads();
  f32x4 z = {0.f,0.f,0.f,0.f};
  f32x4 acc[4] = {z,z,z,z};
  #pragma unroll
  for (int ks = 0; ks < 16; ks++){
    int kh = ks>>2, kw = ks&3;
    #pragma unroll
    for (int mt = 0; mt < 4; mt++){
      int p = mt*16 + ln;
      int oa = p>>3, ob = p&7;
      bf16x8 a = *(const bf16x8*)&in_t[((2*oa+kw)*18 + (2*ob+kh))*32 + quad*8];
      acc[mt] = __builtin_amdgcn_mfma_f32_16x16x32_bf16(a, bfr[ks], acc[mt],0,0,0);
    }
  }
  float s = 0.f, s2 = 0.f;
  float bz = bias[o];
  #pragma unroll
  for (int mt = 0; mt < 4; mt++)
    #pragma unroll
    for (int j = 0; j < 4; j++){
      float v = acc[mt][j] + bz;
      acc[mt][j] = v; s += v; s2 += v*v;
    }
  block_reduce2(s, s2, sbuf);
  float m = s*(1.f/4096.f);
  float rs = rsqrtf(s2*(1.f/4096.f) - m*m + 1e-5f);
  short* op = outp + (size_t)n*4096;
  #pragma unroll
  for (int mt = 0; mt < 4; mt++)
    #pragma unroll
    for (int j = 0; j < 4; j++){
      int p = mt*16 + quad*4 + j;
      int oa = p>>3, ob = p&7;
      op[oa*512 + ob*64 + o] = f2bf(eluf((acc[mt][j]-m)*rs));
    }
}

// ---------------- dec_conv1 MFMA: final bf16 in -> final bf16 relu(LN) out ----------------
__global__ __launch_bounds__(256) void dec_conv1_mfma(
    const short* __restrict__ in, const short* __restrict__ Bd, const float* __restrict__ bias,
    short* __restrict__ outp)
{
  __shared__ __align__(16) short in_t[10*10*64];
  __shared__ float sbuf[16];
  int n = blockIdx.x, tid = threadIdx.x;
  for (int l = tid; l < 10*10*64/4; l += 256) ((unsigned long long*)in_t)[l] = 0ull;
  __syncthreads();
  const short* ip = in + (size_t)n*4096;
  for (int l = tid; l < 1024; l += 256){
    int i4 = l & 15, sb = (l>>4)&7, sa = l>>7;
    *(uint2*)&in_t[((sa+1)*10 + (sb+1))*64 + i4*4] = *(const uint2*)&ip[sa*512 + sb*64 + i4*4];
  }
  int wave = tid>>6, ln = tid&15, quad = (tid>>4)&3;
  int pa = wave & 1, pb = wave >> 1;
  bf16x8 bfr[2][8];
  #pragma unroll
  for (int nt = 0; nt < 2; nt++){
    const short* Brow = Bd + (wave*32 + nt*16 + ln)*256;
    #pragma unroll
    for (int ks = 0; ks < 8; ks++)
      bfr[nt][ks] = *(const bf16x8*)&Brow[ks*32 + quad*8];
  }
  __syncthreads();
  f32x4 z = {0.f,0.f,0.f,0.f};
  f32x4 acc[2][4] = {{z,z,z,z},{z,z,z,z}};
  #pragma unroll
  for (int ks = 0; ks < 8; ks++){
    int tap = ks>>1, ibase = (ks&1)*32 + quad*8;
    int da = tap & 1, db = tap >> 1;
    #pragma unroll
    for (int mt = 0; mt < 4; mt++){
      int p = mt*16 + ln;
      int ta = p>>3, tb = p&7;
      bf16x8 a = *(const bf16x8*)&in_t[((ta+da+pa)*10 + (tb+db+pb))*64 + ibase];
      acc[0][mt] = __builtin_amdgcn_mfma_f32_16x16x32_bf16(a, bfr[0][ks], acc[0][mt],0,0,0);
      acc[1][mt] = __builtin_amdgcn_mfma_f32_16x16x32_bf16(a, bfr[1][ks], acc[1][mt],0,0,0);
    }
  }
  float s = 0.f, s2 = 0.f;
  #pragma unroll
  for (int nt = 0; nt < 2; nt++){
    float bz = bias[nt*16 + ln];
    #pragma unroll
    for (int mt = 0; mt < 4; mt++)
      #pragma unroll
      for (int j = 0; j < 4; j++){
        float v = acc[nt][mt][j] + bz;
        acc[nt][mt][j] = v; s += v; s2 += v*v;
      }
  }
  block_reduce2(s, s2, sbuf);
  float m = s*(1.f/8192.f);
  float rs = rsqrtf(s2*(1.f/8192.f) - m*m + 1e-5f);
  short* op = outp + (size_t)n*8192;
  #pragma unroll
  for (int nt = 0; nt < 2; nt++){
    int o = nt*16 + ln;
    #pragma unroll
    for (int mt = 0; mt < 4; mt++)
      #pragma unroll
      for (int j = 0; j < 4; j++){
        int p = mt*16 + quad*4 + j;
        int ta = p>>3, tb = p&7;
        op[(2*ta+pa)*512 + (2*tb+pb)*32 + o] = f2bf(fmaxf((acc[nt][mt][j]-m)*rs, 0.f));
      }
  }
}

// ---------------- dec_conv2 MFMA: final bf16 in -> final bf16 relu(LN) out ----------------
__global__ __launch_bounds__(256) void dec_conv2_mfma(
    const short* __restrict__ in, const short* __restrict__ Bd, const float* __restrict__ bias,
    short* __restrict__ outp)
{
  __shared__ __align__(16) short in_t[18*18*32];
  __shared__ float sbuf[16];
  int n = blockIdx.x, tid = threadIdx.x;
  for (int l = tid; l < 18*18*32/4; l += 256) ((unsigned long long*)in_t)[l] = 0ull;
  __syncthreads();
  const short* ip = in + (size_t)n*8192;
  for (int l = tid; l < 2048; l += 256){
    int i4 = l & 7, sb = (l>>3)&15, sa = l>>7;
    *(uint2*)&in_t[((sa+1)*18 + (sb+1))*32 + i4*4] = *(const uint2*)&ip[sa*512 + sb*32 + i4*4];
  }
  int wave = tid>>6, ln = tid&15, quad = (tid>>4)&3;
  int pa = wave & 1, pb = wave >> 1;
  bf16x8 bfr[4];
  {
    const short* Brow = Bd + (wave*16 + ln)*128;
    #pragma unroll
    for (int ks = 0; ks < 4; ks++)
      bfr[ks] = *(const bf16x8*)&Brow[ks*32 + quad*8];
  }
  __syncthreads();
  f32x4 z = {0.f,0.f,0.f,0.f};
  f32x4 acc[16] = {z,z,z,z,z,z,z,z,z,z,z,z,z,z,z,z};
  #pragma unroll
  for (int ks = 0; ks < 4; ks++){
    int da = ks & 1, db = ks >> 1;
    #pragma unroll
    for (int mt = 0; mt < 16; mt++){
      int p = mt*16 + ln;
      int ta = p>>4, tb = p&15;
      bf16x8 a = *(const bf16x8*)&in_t[((ta+da+pa)*18 + (tb+db+pb))*32 + quad*8];
      acc[mt] = __builtin_amdgcn_mfma_f32_16x16x32_bf16(a, bfr[ks], acc[mt],0,0,0);
    }
  }
  float s = 0.f, s2 = 0.f;
  float bz = bias[ln];
  #pragma unroll
  for (int mt = 0; mt < 16; mt++)
    #pragma unroll
    for (int j = 0; j < 4; j++){
      float v = acc[mt][j] + bz;
      acc[mt][j] = v; s += v; s2 += v*v;
    }
  block_reduce2(s, s2, sbuf);
  float m = s*(1.f/16384.f);
  float rs = rsqrtf(s2*(1.f/16384.f) - m*m + 1e-5f);
  short* op = outp + (size_t)n*16384;
  #pragma unroll
  for (int mt = 0; mt < 16; mt++)
    #pragma unroll
    for (int j = 0; j < 4; j++){
      int p = mt*16 + quad*4 + j;
      int ta = p>>4, tb = p&15;
      op[(2*ta+pa)*512 + (2*tb+pb)*16 + ln] = f2bf(fmaxf((acc[mt][j]-m)*rs, 0.f));
    }
}

// ---------------- dec_conv3 (final bf16 in) ----------------
__global__ __launch_bounds__(256) void dec_conv3_ig(
    const short* __restrict__ in, const float* __restrict__ CWT, const float* __restrict__ bias,
    float* __restrict__ outp)
{
  __shared__ __align__(16) float in_t[9792];   // [sa34][sb18][i16]
  __shared__ __align__(16) float wl[256];
  int bx = blockIdx.x;
  int n = bx >> 1, b0 = (bx & 1) * 32, tb0 = b0 >> 1;
  int tid = threadIdx.x;
  const short* ip = in + (size_t)n*16384;
  for (int l = tid; l < 9792; l += 256){
    int i = l & 15, sb = (l >> 4) % 18, sap = l / 288;
    int sa = sap - 1, sbg = tb0 - 1 + sb;
    float v = 0.f;
    if ((unsigned)sa < 32u && (unsigned)sbg < 32u)
      v = bf2f(ip[sa*512 + sbg*16 + i]);
    in_t[(sap*18 + sb)*16 + i] = v;
  }
  for (int l = tid; l < 256; l += 256) wl[l] = CWT[l];
  __syncthreads();
  float bv = bias[0];
  int bl = tid & 31, ath = tid >> 5;
  int b = b0 + bl;
  int tb = b >> 1, pb = b & 1;
  float* op = outp + (size_t)n*4096;
  #pragma unroll
  for (int j = 0; j < 8; j++){
    int a = ath*8 + j;
    int ta = a >> 1, pa = a & 1;
    float4 s4 = make_float4(0.f,0.f,0.f,0.f);
    #pragma unroll
    for (int db = 0; db < 2; db++){
      int sb = tb + db + (pb ? 0 : -1);
      int sbl = sb - (tb0 - 1);
      #pragma unroll
      for (int da = 0; da < 2; da++){
        int sa = ta + da + (pa ? 0 : -1);
        int sap = sa + 1;
        const float4* A4 = (const float4*)&in_t[(sap*18 + sbl)*16];
        const float4* B4 = (const float4*)&wl[((pb*2+pa)*4 + db*2+da)*16];
        #pragma unroll
        for (int q = 0; q < 4; q++){
          float4 av = A4[q], bw = B4[q];
          s4.x += av.x*bw.x; s4.y += av.y*bw.y;
          s4.z += av.z*bw.z; s4.w += av.w*bw.w;
        }
      }
    }
    op[a*64 + b] = sigf(bv + s4.x + s4.y + s4.z + s4.w);
  }
}

extern "C" void kernel_launch(void* const* d_in, const int* in_sizes, int n_in,
                              void* d_out, int out_size, void* d_ws, size_t ws_size,
                              hipStream_t stream) {
  const float* x      = (const float*)d_in[0];
  const float* state  = (const float*)d_in[1];
  const float* c1w    = (const float*)d_in[2];
  const float* c1b    = (const float*)d_in[3];
  const float* c2w    = (const float*)d_in[4];
  const float* c2b    = (const float*)d_in[5];
  const float* c3w    = (const float*)d_in[6];
  const float* c3b    = (const float*)d_in[7];
  const float* efc_w  = (const float*)d_in[8];
  const float* efc_b  = (const float*)d_in[9];
  const float* renc_w = (const float*)d_in[10];
  const float* renc_b = (const float*)d_in[11];
  const float* core_w = (const float*)d_in[12];
  const float* core_b = (const float*)d_in[13];
  const float* ctx_w  = (const float*)d_in[14];
  const float* ctx_b  = (const float*)d_in[15];
  const float* att1_w = (const float*)d_in[16];
  const float* att1_b = (const float*)d_in[17];
  const float* att2_w = (const float*)d_in[18];
  const float* att2_b = (const float*)d_in[19];
  const float* out_w  = (const float*)d_in[20];
  const float* out_b  = (const float*)d_in[21];
  const float* dfc1_w = (const float*)d_in[22];
  const float* dfc1_b = (const float*)d_in[23];
  const float* dfc2_w = (const float*)d_in[24];
  const float* dfc2_b = (const float*)d_in[25];
  const float* d1w    = (const float*)d_in[26];
  const float* d1b    = (const float*)d_in[27];
  const float* d2w    = (const float*)d_in[28];
  const float* d2b    = (const float*)d_in[29];
  const float* d3w    = (const float*)d_in[30];
  const float* d3b    = (const float*)d_in[31];

  float* wsf = (float*)d_ws;
  size_t o = 0;
  float* PB   = wsf + o; o += (size_t)1600*1024;    // split-K partials (fp32)
  float* PB2  = wsf + o; o += (size_t)2688*100*4;   // att1 partials (KS=4)
  float* CWT3 = wsf + o; o += 256;
  // bf16 buffers (sizes in shorts; offsets in floats)
  short* E1b  = (short*)(wsf + o); o += (size_t)384*16384/2;   // enc1 final; later dec2 final
  short* E2b  = (short*)(wsf + o); o += (size_t)384*8192/2;    // enc2 final; later dec1 final
  short* E3b  = (short*)(wsf + o); o += (size_t)384*4096/2;    // enc3 final; later G2 final
  short* TOTb = (short*)(wsf + o); o += (size_t)384*1024/2;    // [s1|pad|eff|pad|h]
  short* C1b  = (short*)(wsf + o); o += (size_t)2688*256/2;
  short* XRb  = (short*)(wsf + o); o += (size_t)384*256/2;
  short* G1b  = (short*)(wsf + o); o += (size_t)384*512/2;
  short* SBF  = (short*)(wsf + o); o += (size_t)384*256/2;
  short* BtC2 = (short*)(wsf + o); o += 8192/2;
  short* BtC3 = (short*)(wsf + o); o += 32768/2;
  short* BD1  = (short*)(wsf + o); o += 32768/2;
  short* BD2  = (short*)(wsf + o); o += 8192/2;
  short* BT_efc  = (short*)(wsf + o); o += 2097152/2;
  short* BT_renc = (short*)(wsf + o); o += 64000/2;
  short* BT_core = (short*)(wsf + o); o += 128000/2;
  short* BT_ctx  = (short*)(wsf + o); o += 64000/2;
  short* BT_att1 = (short*)(wsf + o); o += 25600/2;
  short* BT_out  = (short*)(wsf + o); o += 256000/2;
  short* BT_dfc1 = (short*)(wsf + o); o += 131072/2;
  short* BT_dfc2 = (short*)(wsf + o); o += 2097152/2;
  short* D1b = E2b;
  short* D2b = E1b;
  short* G2b = E3b;

  float* xout = (float*)d_out;
  float* sout = xout + (size_t)384*4096;

  // one prep kernel: weight transposes + folds + state cvt + TOT pad zero
  prep_combined<<<1448, 256, 0, stream>>>(
      efc_w, BT_efc, dfc2_w, BT_dfc2, out_w, BT_out, core_w, BT_core,
      dfc1_w, BT_dfc1, renc_w, BT_renc, ctx_w, BT_ctx, att1_w, BT_att1,
      d3w, CWT3, c2w, BtC2, c3w, BtC3, d1w, BD1, d2w, BD2, state, SBF, TOTb);

  // encoder (each conv writes FINAL activated bf16)
  enc_conv1_ig<<<384, 256, 0, stream>>>(x, c1w, c1b, E1b);
  enc_conv2_mfma<<<384, 256, 0, stream>>>(E1b, BtC2, c2b, E2b);
  enc_conv3_mfma<<<384, 256, 0, stream>>>(E2b, BtC3, c3b, E3b);
  gemm_mfma<<<dim3(8,6,8), 256, 0, stream>>>(E3b, BT_efc, PB, 384, 512, 4096, 512);
  reduce_ln<<<384, 256, 0, stream>>>(PB, efc_b, TOTb+512, 384, 512, 8, 1024, 2, 1);

  // state path
  gemm_mfma<<<dim3(4,6,8), 256, 0, stream>>>(SBF, BT_renc, PB, 384, 250, 256, 32);
  reduce_ln<<<384, 256, 0, stream>>>(PB, renc_b, TOTb, 384, 250, 8, 1024, 1, 1);
  gemm_core_mfma<<<dim3(4,42,2), 256, 0, stream>>>(TOTb, BT_core, PB, 2688, 250, 256);
  reduce_ln<<<2688, 256, 0, stream>>>(PB, core_b, C1b, 2688, 250, 2, 256, 1, 1);
  gemm_mfma<<<dim3(4,42,2), 256, 0, stream>>>(C1b, BT_ctx, PB, 2688, 250, 256, 128);
  gemm_mfma<<<dim3(2,42,4), 256, 0, stream>>>(C1b, BT_att1, PB2, 2688, 100, 256, 64);
  ctx_att_effect<<<384, 448, 0, stream>>>(PB, ctx_b, PB2, att1_b, att2_w, att2_b, TOTb);

  // combine
  gemm_mfma<<<dim3(4,6,8), 256, 0, stream>>>(TOTb, BT_out, PB, 384, 250, 1024, 128);
  reduce_ns<<<384, 256, 0, stream>>>(PB, out_b, XRb, sout, 384, 250, 8);

  // decoder FC
  gemm_mfma<<<dim3(8,6,4), 256, 0, stream>>>(XRb, BT_dfc1, PB, 384, 512, 256, 64);
  reduce_ln<<<384, 256, 0, stream>>>(PB, dfc1_b, G1b, 384, 512, 4, 512, 1, 1);
  gemm_mfma<<<dim3(64,6,1), 256, 0, stream>>>(G1b, BT_dfc2, PB, 384, 4096, 512, 512);
  reduce_ln<<<384, 256, 0, stream>>>(PB, dfc2_b, G2b, 384, 4096, 1, 4096, 1, 1);

  // decoder convs (final activated bf16 chain)
  dec_conv1_mfma<<<384, 256, 0, stream>>>(G2b, BD1, d1b, D1b);
  dec_conv2_mfma<<<384, 256, 0, stream>>>(D1b, BD2, d2b, D2b);
  dec_conv3_ig<<<768, 256, 0, stream>>>(D2b, CWT3, d3b, xout);

  (void)in_sizes; (void)n_in; (void)out_size; (void)ws_size;
}

// Round 15
// 322.472 us; speedup vs baseline: 1.4577x; 1.0374x over previous
//
#include <hip/hip_runtime.h>
#include <hip/hip_bf16.h>
#include <math.h>

typedef __attribute__((ext_vector_type(8))) short bf16x8;
typedef __attribute__((ext_vector_type(4))) float f32x4;

__device__ __forceinline__ float eluf(float v){ return v > 0.f ? v : expm1f(v); }
__device__ __forceinline__ float sigf(float v){ return 1.f/(1.f+expf(-v)); }
__device__ __forceinline__ unsigned short f2bf(float f){
  unsigned u = __float_as_uint(f);
  u += 0x7FFFu + ((u >> 16) & 1u);          // round-to-nearest-even
  return (unsigned short)(u >> 16);
}
__device__ __forceinline__ float bf2f(short s){
  return __uint_as_float(((unsigned)(unsigned short)s) << 16);
}

// ---------------- block-wide sum & sumsq reduction ----------------
__device__ __forceinline__ void block_reduce2(float& a, float& b, float* sbuf){
  __syncthreads();
  for (int off = 32; off; off >>= 1){
    a += __shfl_down(a, off);
    b += __shfl_down(b, off);
  }
  int lane = threadIdx.x & 63, w = threadIdx.x >> 6;
  if (lane == 0){ sbuf[2*w] = a; sbuf[2*w+1] = b; }
  __syncthreads();
  if (threadIdx.x == 0){
    int nw = blockDim.x >> 6;
    float sa = 0.f, sb = 0.f;
    for (int i = 0; i < nw; i++){ sa += sbuf[2*i]; sb += sbuf[2*i+1]; }
    sbuf[0] = sa; sbuf[1] = sb;
  }
  __syncthreads();
  a = sbuf[0]; b = sbuf[1];
}

// ---------------- prep helpers ----------------
__device__ __forceinline__ float fold_sum(const float* __restrict__ w, int O, int I,
                                          int o, int i, int pa, int pb, int da, int db){
  float s = 0.f;
  for (int kh = 0; kh < 4; kh++){
    bool inh = (pb==0) ? (db==0 ? (kh==0) : (kh>=1)) : (db==0 ? (kh<=2) : (kh==3));
    if (!inh) continue;
    for (int kw = 0; kw < 4; kw++){
      bool inw = (pa==0) ? (da==0 ? (kw==0) : (kw>=1)) : (da==0 ? (kw<=2) : (kw==3));
      if (!inw) continue;
      s += w[((o*I + i)*4 + kh)*4 + kw];
    }
  }
  return s;
}
__device__ __forceinline__ void fold_elem(const float* __restrict__ w, float* __restrict__ CW,
                                          int O, int I, int l){
  int o = l % O; int q = l / O;
  int da = q & 1, db = (q>>1)&1, pa = (q>>2)&1, pb = (q>>3)&1, i = q>>4;
  CW[(((pb*2+pa)*4 + db*2+da)*I + i)*O + o] = fold_sum(w, O, I, o, i, pa, pb, da, db);
}
__device__ __forceinline__ void cvtc2_elem(const float* __restrict__ w, short* __restrict__ D, int l){
  int i = l & 15, t = (l>>4) & 15, o = l>>8;        // k = t*16 + i
  D[l] = (short)f2bf(w[(o*16 + i)*16 + t]);
}
__device__ __forceinline__ void cvtc3_elem(const float* __restrict__ w, short* __restrict__ D, int l){
  int i = l & 31, t = (l>>5) & 15, o = l>>9;        // k = t*32 + i
  D[l] = (short)f2bf(w[(o*32 + i)*16 + t]);
}
__device__ __forceinline__ void foldd1_elem(const float* __restrict__ w, short* __restrict__ D, int l){
  int i = l & 63, tap = (l>>6)&3, o = (l>>8)&31, ph = l>>13;
  D[l] = (short)f2bf(fold_sum(w, 32, 64, o, i, ph&1, ph>>1, tap&1, tap>>1));
}
__device__ __forceinline__ void foldd2_elem(const float* __restrict__ w, short* __restrict__ D, int l){
  int i = l & 31, tap = (l>>5)&3, o = (l>>7)&15, ph = l>>11;
  D[l] = (short)f2bf(fold_sum(w, 16, 32, o, i, ph&1, ph>>1, tap&1, tap>>1));
}

// ---------------- combined prep: weight transposes (blocks 0..1191) + small packs ----------------
__global__ __launch_bounds__(256) void prep_combined(
  const float* __restrict__ efc,  short* __restrict__ Defc,
  const float* __restrict__ dfc2, short* __restrict__ Ddfc2,
  const float* __restrict__ outw, short* __restrict__ Dout,
  const float* __restrict__ corew,short* __restrict__ Dcore,
  const float* __restrict__ dfc1, short* __restrict__ Ddfc1,
  const float* __restrict__ renc, short* __restrict__ Drenc,
  const float* __restrict__ ctx,  short* __restrict__ Dctx,
  const float* __restrict__ att1, short* __restrict__ Datt1,
  const float* __restrict__ d3w, float* __restrict__ CWT3,
  const float* __restrict__ c2w, short* __restrict__ BtC2,
  const float* __restrict__ c3w, short* __restrict__ BtC3,
  const float* __restrict__ d1w, short* __restrict__ BD1,
  const float* __restrict__ d2w, short* __restrict__ BD2,
  const float* __restrict__ state, short* __restrict__ SBF,
  short* __restrict__ TOTb)
{
  int bx = blockIdx.x;
  if (bx >= 1192){
    const int F3=256, P2=F3+8192, P3=P2+32768, P4=P3+32768, P5=P4+8192,
              ST=P5+98304, TOTAL=ST+4608;
    for (int l = (bx-1192)*256 + threadIdx.x; l < TOTAL; l += 256*256){
      if (l < F3)      fold_elem(d3w, CWT3, 1, 16, l);
      else if (l < P2) cvtc2_elem(c2w, BtC2, l - F3);
      else if (l < P3) cvtc3_elem(c3w, BtC3, l - P2);
      else if (l < P4) foldd1_elem(d1w, BD1, l - P3);
      else if (l < P5) foldd2_elem(d2w, BD2, l - P4);
      else if (l < ST){
        int q = l - P5;             // state -> bf16 [384][256], zero pad
        int n = q >> 8, k = q & 255;
        SBF[q] = (k < 250) ? (short)f2bf(state[n*250 + k]) : (short)0;
      } else {
        int q = l - ST;             // zero TOT pad cols: 250..255, 506..511
        int row = q / 12, cc = q % 12;
        int col = cc < 6 ? 250 + cc : 506 + (cc - 6);
        TOTb[row*1024 + col] = 0;
      }
    }
    return;
  }
  const float* W; short* D; int K, N, Kp, base, mode = 0;
  if      (bx < 512) { W=efc;  D=Defc;  K=4096; N=512;  Kp=4096; base=0;    }
  else if (bx < 1024){ W=dfc2; D=Ddfc2; K=512;  N=4096; Kp=512;  base=512;  }
  else if (bx < 1088){ W=outw; D=Dout;  K=1012; N=250;  Kp=1024; base=1024; mode=2; }
  else if (bx < 1120){ W=corew;D=Dcore; K=500;  N=250;  Kp=512;  base=1088; mode=1; }
  else if (bx < 1152){ W=dfc1; D=Ddfc1; K=250;  N=512;  Kp=256;  base=1120; }
  else if (bx < 1168){ W=renc; D=Drenc; K=250;  N=250;  Kp=256;  base=1152; }
  else if (bx < 1184){ W=ctx;  D=Dctx;  K=250;  N=250;  Kp=256;  base=1168; }
  else               { W=att1; D=Datt1; K=250;  N=100;  Kp=256;  base=1184; }
  int t = bx - base;
  int tpr = Kp >> 6;
  int tk = t % tpr, tn = t / tpr;
  __shared__ short tile[64][65];
  int c = threadIdx.x & 63, r4 = threadIdx.x >> 6;
  int n0 = tn*64, k0 = tk*64;
  #pragma unroll 4
  for (int p = 0; p < 16; p++){
    int r = r4*16 + p;
    int k = k0 + r, n = n0 + c;
    int ksrc = k; bool valid;
    if (mode == 0) valid = (k < K);
    else if (mode == 1){ valid = (k < 250) || (k >= 256 && k < 506); ksrc = k < 256 ? k : k - 6; }
    else { valid = (k < 250) || (k >= 256 && k < 506) || (k >= 512);
           ksrc = k < 256 ? k : (k < 512 ? k - 6 : k - 12); }
    float v = (valid && n < N) ? W[(size_t)ksrc*N + n] : 0.f;
    tile[c][r] = (short)f2bf(v);
  }
  __syncthreads();
  #pragma unroll 4
  for (int p = 0; p < 16; p++){
    int nn = r4*16 + p;
    int n = n0 + nn;
    if (n < N) D[(size_t)n*Kp + k0 + c] = tile[nn][c];
  }
}

// ---------------- MFMA bf16 split-K GEMM, bf16 A ----------------
__global__ __launch_bounds__(256) void gemm_mfma(
    const short* __restrict__ Ab, const short* __restrict__ Bt,
    float* __restrict__ P, int M, int N, int Kp, int Kc)
{
  __shared__ __align__(16) short As[64*32];
  __shared__ __align__(16) short Bs[64*32];
  int tid = threadIdx.x;
  int bm = blockIdx.y*64, bn = blockIdx.x*64;
  int kb = blockIdx.z * Kc;
  int kend = kb + Kc;

  int r = tid >> 2, c = tid & 3;
  const short* Arow = Ab + (size_t)(bm + r)*Kp;
  int gn = bn + r;
  bool bval = gn < N;
  const short* Brow = Bt + (size_t)gn*Kp;

  uint4 hA, hB;
  auto load_regs = [&](int k0){
    hA = *(const uint4*)&Arow[k0 + c*8];
    hB = bval ? *(const uint4*)&Brow[k0 + c*8] : make_uint4(0,0,0,0);
  };
  auto write_lds = [&](){
    *(uint4*)&As[r*32 + c*8] = hA;
    *(uint4*)&Bs[r*32 + c*8] = hB;
  };

  int wave = tid >> 6;
  int ln = tid & 15, quad = (tid >> 4) & 3;
  int wr = (wave >> 1) * 32, wc = (wave & 1) * 32;

  f32x4 zero = {0.f, 0.f, 0.f, 0.f};
  f32x4 acc[2][2] = {{zero, zero}, {zero, zero}};

  load_regs(kb);
  write_lds();
  __syncthreads();
  for (int k0 = kb; k0 < kend; k0 += 32){
    int nxt = k0 + 32;
    if (nxt < kend) load_regs(nxt);
    bf16x8 a0 = *(const bf16x8*)&As[(wr +      ln)*32 + quad*8];
    bf16x8 a1 = *(const bf16x8*)&As[(wr + 16 + ln)*32 + quad*8];
    bf16x8 b0 = *(const bf16x8*)&Bs[(wc +      ln)*32 + quad*8];
    bf16x8 b1 = *(const bf16x8*)&Bs[(wc + 16 + ln)*32 + quad*8];
    acc[0][0] = __builtin_amdgcn_mfma_f32_16x16x32_bf16(a0, b0, acc[0][0], 0, 0, 0);
    acc[0][1] = __builtin_amdgcn_mfma_f32_16x16x32_bf16(a0, b1, acc[0][1], 0, 0, 0);
    acc[1][0] = __builtin_amdgcn_mfma_f32_16x16x32_bf16(a1, b0, acc[1][0], 0, 0, 0);
    acc[1][1] = __builtin_amdgcn_mfma_f32_16x16x32_bf16(a1, b1, acc[1][1], 0, 0, 0);
    __syncthreads();
    if (nxt < kend){ write_lds(); __syncthreads(); }
  }

  float* Pout = P + (size_t)blockIdx.z*M*N;
  #pragma unroll
  for (int t = 0; t < 2; t++)
    #pragma unroll
    for (int u = 0; u < 2; u++)
      #pragma unroll
      for (int j = 0; j < 4; j++){
        int row = bm + wr + t*16 + quad*4 + j;
        int col = bn + wc + u*16 + ln;
        if (col < N) Pout[(size_t)row*N + col] = acc[t][u][j];
      }
}

// ---------------- core GEMM: A gathered from padded TOT (pair fusion) ----------------
__global__ __launch_bounds__(256) void gemm_core_mfma(
    const short* __restrict__ Tb, const short* __restrict__ Bt,
    float* __restrict__ P, int M, int N, int Kc)
{
  __shared__ __align__(16) short As[64*32];
  __shared__ __align__(16) short Bs[64*32];
  int tid = threadIdx.x;
  int bm = blockIdx.y*64, bn = blockIdx.x*64;
  int kb = blockIdx.z * Kc;
  int kend = kb + Kc;

  int r = tid >> 2, c = tid & 3;
  int gr = bm + r;
  int jj2 = gr % 7, fi2 = gr / 7;
  int ii = fi2 & 7, j2 = fi2 >> 3;
  int jidx = jj2 < ii ? jj2 : jj2 + 1;
  const short* own = Tb + (size_t)fi2*1024;
  const short* oth = Tb + (size_t)(j2*8 + jidx)*1024;
  int gn = bn + r;
  bool bval = gn < N;
  const short* Brow = Bt + (size_t)gn*512;

  uint4 hA, hB;
  auto load_regs = [&](int k0){
    int kk = k0 + c*8;
    const short* src = (kk & 256) ? oth : own;
    hA = *(const uint4*)&src[kk & 255];
    hB = bval ? *(const uint4*)&Brow[kk] : make_uint4(0,0,0,0);
  };
  auto write_lds = [&](){
    *(uint4*)&As[r*32 + c*8] = hA;
    *(uint4*)&Bs[r*32 + c*8] = hB;
  };

  int wave = tid >> 6;
  int ln = tid & 15, quad = (tid >> 4) & 3;
  int wr = (wave >> 1) * 32, wc = (wave & 1) * 32;

  f32x4 zero = {0.f, 0.f, 0.f, 0.f};
  f32x4 acc[2][2] = {{zero, zero}, {zero, zero}};

  load_regs(kb);
  write_lds();
  __syncthreads();
  for (int k0 = kb; k0 < kend; k0 += 32){
    int nxt = k0 + 32;
    if (nxt < kend) load_regs(nxt);
    bf16x8 a0 = *(const bf16x8*)&As[(wr +      ln)*32 + quad*8];
    bf16x8 a1 = *(const bf16x8*)&As[(wr + 16 + ln)*32 + quad*8];
    bf16x8 b0 = *(const bf16x8*)&Bs[(wc +      ln)*32 + quad*8];
    bf16x8 b1 = *(const bf16x8*)&Bs[(wc + 16 + ln)*32 + quad*8];
    acc[0][0] = __builtin_amdgcn_mfma_f32_16x16x32_bf16(a0, b0, acc[0][0], 0, 0, 0);
    acc[0][1] = __builtin_amdgcn_mfma_f32_16x16x32_bf16(a0, b1, acc[0][1], 0, 0, 0);
    acc[1][0] = __builtin_amdgcn_mfma_f32_16x16x32_bf16(a1, b0, acc[1][0], 0, 0, 0);
    acc[1][1] = __builtin_amdgcn_mfma_f32_16x16x32_bf16(a1, b1, acc[1][1], 0, 0, 0);
    __syncthreads();
    if (nxt < kend){ write_lds(); __syncthreads(); }
  }

  float* Pout = P + (size_t)blockIdx.z*M*N;
  #pragma unroll
  for (int t = 0; t < 2; t++)
    #pragma unroll
    for (int u = 0; u < 2; u++)
      #pragma unroll
      for (int j = 0; j < 4; j++){
        int row = bm + wr + t*16 + quad*4 + j;
        int col = bn + wc + u*16 + ln;
        if (col < N) Pout[(size_t)row*N + col] = acc[t][u][j];
      }
}

// ---------------- fused: out = act(LN_last(sum_ks P + bias)); obf: write bf16 ----------------
__global__ __launch_bounds__(256) void reduce_ln(
    const float* __restrict__ Pp, const float* __restrict__ bias,
    void* __restrict__ outp, int M, int N, int KS, int os, int act, int obf)
{
  __shared__ float rowbuf[4096];
  __shared__ float sbuf[16];
  int row = blockIdx.x;
  size_t MN = (size_t)M*N;
  float s = 0.f, s2 = 0.f;
  for (int c = threadIdx.x; c < N; c += 256){
    float v = bias[c];
    for (int ks = 0; ks < KS; ks++) v += Pp[ks*MN + (size_t)row*N + c];
    rowbuf[c] = v; s += v; s2 += v*v;
  }
  block_reduce2(s, s2, sbuf);
  float m = s / N;
  float r = rsqrtf(s2/N - m*m + 1e-5f);
  for (int c = threadIdx.x; c < N; c += 256){
    float v = (rowbuf[c]-m)*r;
    if (act == 1) v = fmaxf(v, 0.f);
    else if (act == 2) v = eluf(v);
    else if (act == 3) v = tanhf(v);
    if (obf) ((short*)outp)[(size_t)row*os + c] = f2bf(v);
    else     ((float*)outp)[(size_t)row*os + c] = v;
  }
}

// ---------------- fused NS: XR bf16, state_out fp32 ----------------
__global__ __launch_bounds__(256) void reduce_ns(
    const float* __restrict__ Pp, const float* __restrict__ bias,
    short* __restrict__ XRb, float* __restrict__ so, int M, int N, int KS)
{
  __shared__ float rowbuf[256];
  __shared__ float sbuf[16];
  int row = blockIdx.x;
  size_t MN = (size_t)M*N;
  float s = 0.f, s2 = 0.f;
  for (int c = threadIdx.x; c < N; c += 256){
    float v = bias[c];
    for (int ks = 0; ks < KS; ks++) v += Pp[ks*MN + (size_t)row*N + c];
    rowbuf[c] = v; s += v; s2 += v*v;
  }
  block_reduce2(s, s2, sbuf);
  float m = s / N;
  float r = rsqrtf(s2/N - m*m + 1e-5f);
  for (int c = threadIdx.x; c < N; c += 256){
    float v = rowbuf[c];
    XRb[(size_t)row*256 + c] = f2bf(sigf((v-m)*r));
    so[(size_t)row*N + c] = sigf(v);
  }
}

// ---------------- ctx/att1 LN + att2 + effect, wave-parallel (7 waves) ----------------
__global__ __launch_bounds__(448) void ctx_att_effect(
    const float* __restrict__ Pc, const float* __restrict__ ctx_b,
    const float* __restrict__ Pa, const float* __restrict__ att1_b,
    const float* __restrict__ w2, const float* __restrict__ b2,
    short* __restrict__ tot)
{
  __shared__ float ctxs[7][250];
  __shared__ float att_s[7];
  int fi = blockIdx.x, tid = threadIdx.x;
  int jj = tid >> 6, lane = tid & 63;
  const size_t MN = (size_t)2688*250, MN2 = (size_t)2688*100;
  int row = fi*7 + jj;
  // ctx: LN + relu
  float vv[4];
  float s = 0.f, s2 = 0.f;
  #pragma unroll
  for (int t = 0; t < 4; t++){
    int c = lane + t*64;
    float v = 0.f;
    if (c < 250) v = ctx_b[c] + Pc[(size_t)row*250 + c] + Pc[MN + (size_t)row*250 + c];
    vv[t] = v; s += v; s2 += v*v;
  }
  #pragma unroll
  for (int off = 32; off; off >>= 1){ s += __shfl_down(s, off); s2 += __shfl_down(s2, off); }
  s = __shfl(s, 0); s2 = __shfl(s2, 0);
  float m = s*(1.f/250.f);
  float r = rsqrtf(s2*(1.f/250.f) - m*m + 1e-5f);
  #pragma unroll
  for (int t = 0; t < 4; t++){
    int c = lane + t*64;
    if (c < 250) ctxs[jj][c] = fmaxf((vv[t]-m)*r, 0.f);
  }
  // att1: LN + tanh + dot(w2) + sigmoid
  float va[2];
  s = 0.f; s2 = 0.f;
  #pragma unroll
  for (int t = 0; t < 2; t++){
    int c = lane + t*64;
    float v = 0.f;
    if (c < 100){
      v = att1_b[c];
      #pragma unroll
      for (int ks = 0; ks < 4; ks++) v += Pa[ks*MN2 + (size_t)row*100 + c];
    }
    va[t] = v; s += v; s2 += v*v;
  }
  #pragma unroll
  for (int off = 32; off; off >>= 1){ s += __shfl_down(s, off); s2 += __shfl_down(s2, off); }
  s = __shfl(s, 0); s2 = __shfl(s2, 0);
  m = s*0.01f;
  r = rsqrtf(s2*0.01f - m*m + 1e-5f);
  float d = 0.f;
  #pragma unroll
  for (int t = 0; t < 2; t++){
    int c = lane + t*64;
    if (c < 100) d += tanhf((va[t]-m)*r)*w2[c];
  }
  #pragma unroll
  for (int off = 32; off; off >>= 1) d += __shfl_down(d, off);
  if (lane == 0) att_s[jj] = sigf(d + b2[0]);
  __syncthreads();
  for (int h = tid; h < 250; h += 448){
    float sum = 0.f;
    #pragma unroll
    for (int q = 0; q < 7; q++) sum += ctxs[q][h]*att_s[q];
    tot[(size_t)fi*1024 + 256 + h] = f2bf(sum);
  }
}

// ---------------- enc_conv1: x(n,64,64) -> FINAL bf16 elu(LN) (n,32,32,16) ----------------
__global__ __launch_bounds__(256) void enc_conv1_ig(
    const float* __restrict__ x, const float* __restrict__ w, const float* __restrict__ bias,
    short* __restrict__ outp)
{
  __shared__ __align__(16) float in_t[66*68];
  __shared__ short rawb[16384];
  __shared__ float sbuf[16];
  int n = blockIdx.x, tid = threadIdx.x;
  for (int l = tid; l < 66*68; l += 256) in_t[l] = 0.f;
  __syncthreads();
  const float* xin = x + (size_t)n*4096;
  for (int l4 = tid; l4 < 1024; l4 += 256){
    float4 v = *(const float4*)&xin[l4*4];
    int aa = (l4*4) >> 6, bb = (l4*4) & 63;
    float* dst = &in_t[(aa+1)*68 + bb + 1];
    dst[0]=v.x; dst[1]=v.y; dst[2]=v.z; dst[3]=v.w;
  }
  int o = tid & 15;
  float wr[16];
  #pragma unroll
  for (int t = 0; t < 16; t++) wr[t] = w[o*16 + t];
  float bv = bias[o];
  __syncthreads();
  float s = 0.f, s2 = 0.f;
  for (int r = 0; r < 64; r++){
    int idx = tid + (r<<8);
    int bq = (idx>>4)&31, aq = idx>>9;
    int a0 = 2*aq, b0 = 2*bq;
    float acc = bv;
    #pragma unroll
    for (int kw = 0; kw < 4; kw++){
      const float* row = &in_t[(a0+kw)*68 + b0];
      float2 p0 = *(const float2*)&row[0];
      float2 p1 = *(const float2*)&row[2];
      acc += p0.x*wr[0*4+kw] + p0.y*wr[1*4+kw] + p1.x*wr[2*4+kw] + p1.y*wr[3*4+kw];
    }
    rawb[idx] = f2bf(acc);
    s += acc; s2 += acc*acc;
  }
  block_reduce2(s, s2, sbuf);
  float m = s*(1.f/16384.f);
  float rs = rsqrtf(s2*(1.f/16384.f) - m*m + 1e-5f);
  short* op = outp + (size_t)n*16384;
  for (int l = tid; l < 16384; l += 256){
    float v = bf2f(rawb[l]);
    op[l] = f2bf(eluf((v-m)*rs));
  }
}

// ---------------- fused enc_conv2+3: E1b final bf16 -> E3b final bf16 (one block/sample) ----------------
__global__ __launch_bounds__(256) void enc_conv23_mfma(
    const short* __restrict__ in, const short* __restrict__ Bt2, const float* __restrict__ bias2,
    const short* __restrict__ Bt3, const float* __restrict__ bias3, short* __restrict__ outp)
{
  __shared__ __align__(16) short smem[34*34*16];   // conv2 staging; reused for conv3 (18*18*32)
  __shared__ float sbuf[16];
  int n = blockIdx.x, tid = threadIdx.x;
  for (int l = tid; l < 34*34*16/4; l += 256) ((unsigned long long*)smem)[l] = 0ull;
  __syncthreads();
  const short* ip = in + (size_t)n*16384;
  for (int l = tid; l < 4096; l += 256){
    int i4 = l & 3, bb = (l>>2) & 31, aa = l>>7;
    *(uint2*)&smem[((aa+1)*34 + (bb+1))*16 + i4*4] = *(const uint2*)&ip[aa*512 + bb*16 + i4*4];
  }
  int wave = tid>>6, ln = tid&15, quad = (tid>>4)&3;
  bf16x8 bfr[2][8];
  #pragma unroll
  for (int nt = 0; nt < 2; nt++){
    const short* Brow = Bt2 + (nt*16 + ln)*256;
    #pragma unroll
    for (int ks = 0; ks < 8; ks++)
      bfr[nt][ks] = *(const bf16x8*)&Brow[ks*32 + quad*8];
  }
  __syncthreads();
  f32x4 z = {0.f,0.f,0.f,0.f};
  f32x4 acc[2][4] = {{z,z,z,z},{z,z,z,z}};
  int tapq = quad>>1, io = (quad&1)*8;
  #pragma unroll
  for (int ks = 0; ks < 8; ks++){
    int t = 2*ks + tapq;
    int kh = t>>2, kw = t&3;
    #pragma unroll
    for (int mt = 0; mt < 4; mt++){
      int p = (wave*4 + mt)*16 + ln;
      int oa = p>>4, ob = p&15;
      bf16x8 a = *(const bf16x8*)&smem[((2*oa+kw)*34 + (2*ob+kh))*16 + io];
      acc[0][mt] = __builtin_amdgcn_mfma_f32_16x16x32_bf16(a, bfr[0][ks], acc[0][mt],0,0,0);
      acc[1][mt] = __builtin_amdgcn_mfma_f32_16x16x32_bf16(a, bfr[1][ks], acc[1][mt],0,0,0);
    }
  }
  float s = 0.f, s2 = 0.f;
  #pragma unroll
  for (int nt = 0; nt < 2; nt++){
    float bz = bias2[nt*16 + ln];
    #pragma unroll
    for (int mt = 0; mt < 4; mt++)
      #pragma unroll
      for (int j = 0; j < 4; j++){
        float v = acc[nt][mt][j] + bz;
        acc[nt][mt][j] = v; s += v; s2 += v*v;
      }
  }
  block_reduce2(s, s2, sbuf);   // final barrier also guards smem reuse
  float m2 = s*(1.f/8192.f);
  float rs2 = rsqrtf(s2*(1.f/8192.f) - m2*m2 + 1e-5f);
  // conv3 B-frags (global, no LDS dependency)
  int o3 = wave*16 + ln;
  bf16x8 bfr3[16];
  {
    const short* Brow = Bt3 + o3*512;
    #pragma unroll
    for (int ks = 0; ks < 16; ks++)
      bfr3[ks] = *(const bf16x8*)&Brow[ks*32 + quad*8];
  }
  // conv3 staging: zero 18*18*32 region, scatter activated conv2 outputs
  for (int l = tid; l < 2592; l += 256) ((unsigned long long*)smem)[l] = 0ull;
  __syncthreads();
  #pragma unroll
  for (int nt = 0; nt < 2; nt++){
    int o = nt*16 + ln;
    #pragma unroll
    for (int mt = 0; mt < 4; mt++)
      #pragma unroll
      for (int j = 0; j < 4; j++){
        int p = (wave*4 + mt)*16 + quad*4 + j;
        int oa = p>>4, ob = p&15;
        smem[((oa+1)*18 + (ob+1))*32 + o] = f2bf(eluf((acc[nt][mt][j]-m2)*rs2));
      }
  }
  __syncthreads();
  f32x4 acc3[4] = {z,z,z,z};
  #pragma unroll
  for (int ks = 0; ks < 16; ks++){
    int kh = ks>>2, kw = ks&3;
    #pragma unroll
    for (int mt = 0; mt < 4; mt++){
      int p = mt*16 + ln;
      int oa = p>>3, ob = p&7;
      bf16x8 a = *(const bf16x8*)&smem[((2*oa+kw)*18 + (2*ob+kh))*32 + quad*8];
      acc3[mt] = __builtin_amdgcn_mfma_f32_16x16x32_bf16(a, bfr3[ks], acc3[mt],0,0,0);
    }
  }
  s = 0.f; s2 = 0.f;
  float bz3 = bias3[o3];
  #pragma unroll
  for (int mt = 0; mt < 4; mt++)
    #pragma unroll
    for (int j = 0; j < 4; j++){
      float v = acc3[mt][j] + bz3;
      acc3[mt][j] = v; s += v; s2 += v*v;
    }
  block_reduce2(s, s2, sbuf);
  float m3 = s*(1.f/4096.f);
  float rs3 = rsqrtf(s2*(1.f/4096.f) - m3*m3 + 1e-5f);
  short* op = outp + (size_t)n*4096;
  #pragma unroll
  for (int mt = 0; mt < 4; mt++)
    #pragma unroll
    for (int j = 0; j < 4; j++){
      int p = mt*16 + quad*4 + j;
      int oa = p>>3, ob = p&7;
      op[oa*512 + ob*64 + o3] = f2bf(eluf((acc3[mt][j]-m3)*rs3));
    }
}

// ---------------- fused dec_conv1+2: G2b final bf16 -> D2b final bf16 (one block/sample) ----------------
__global__ __launch_bounds__(256) void dec_conv12_mfma(
    const short* __restrict__ in, const short* __restrict__ Bd1, const float* __restrict__ bias1,
    const short* __restrict__ Bd2, const float* __restrict__ bias2, short* __restrict__ outp)
{
  __shared__ __align__(16) short smem[18*18*32];   // conv1 staging (10*10*64) then conv2 staging
  __shared__ float sbuf[16];
  int n = blockIdx.x, tid = threadIdx.x;
  for (int l = tid; l < 1600; l += 256) ((unsigned long long*)smem)[l] = 0ull;   // 6400 shorts
  __syncthreads();
  const short* ip = in + (size_t)n*4096;
  for (int l = tid; l < 1024; l += 256){
    int i4 = l & 15, sb = (l>>4)&7, sa = l>>7;
    *(uint2*)&smem[((sa+1)*10 + (sb+1))*64 + i4*4] = *(const uint2*)&ip[sa*512 + sb*64 + i4*4];
  }
  int wave = tid>>6, ln = tid&15, quad = (tid>>4)&3;
  int pa = wave & 1, pb = wave >> 1;
  bf16x8 bfr1[2][8];
  #pragma unroll
  for (int nt = 0; nt < 2; nt++){
    const short* Brow = Bd1 + (wave*32 + nt*16 + ln)*256;
    #pragma unroll
    for (int ks = 0; ks < 8; ks++)
      bfr1[nt][ks] = *(const bf16x8*)&Brow[ks*32 + quad*8];
  }
  __syncthreads();
  f32x4 z = {0.f,0.f,0.f,0.f};
  f32x4 acc[2][4] = {{z,z,z,z},{z,z,z,z}};
  #pragma unroll
  for (int ks = 0; ks < 8; ks++){
    int tap = ks>>1, ibase = (ks&1)*32 + quad*8;
    int da = tap & 1, db = tap >> 1;
    #pragma unroll
    for (int mt = 0; mt < 4; mt++){
      int p = mt*16 + ln;
      int ta = p>>3, tb = p&7;
      bf16x8 a = *(const bf16x8*)&smem[((ta+da+pa)*10 + (tb+db+pb))*64 + ibase];
      acc[0][mt] = __builtin_amdgcn_mfma_f32_16x16x32_bf16(a, bfr1[0][ks], acc[0][mt],0,0,0);
      acc[1][mt] = __builtin_amdgcn_mfma_f32_16x16x32_bf16(a, bfr1[1][ks], acc[1][mt],0,0,0);
    }
  }
  float s = 0.f, s2 = 0.f;
  #pragma unroll
  for (int nt = 0; nt < 2; nt++){
    float bz = bias1[nt*16 + ln];
    #pragma unroll
    for (int mt = 0; mt < 4; mt++)
      #pragma unroll
      for (int j = 0; j < 4; j++){
        float v = acc[nt][mt][j] + bz;
        acc[nt][mt][j] = v; s += v; s2 += v*v;
      }
  }
  block_reduce2(s, s2, sbuf);   // final barrier also guards smem reuse
  float m1 = s*(1.f/8192.f);
  float rs1 = rsqrtf(s2*(1.f/8192.f) - m1*m1 + 1e-5f);
  bf16x8 bfr2[4];
  {
    const short* Brow = Bd2 + (wave*16 + ln)*128;
    #pragma unroll
    for (int ks = 0; ks < 4; ks++)
      bfr2[ks] = *(const bf16x8*)&Brow[ks*32 + quad*8];
  }
  for (int l = tid; l < 2592; l += 256) ((unsigned long long*)smem)[l] = 0ull;   // 10368 shorts
  __syncthreads();
  #pragma unroll
  for (int nt = 0; nt < 2; nt++){
    int o = nt*16 + ln;
    #pragma unroll
    for (int mt = 0; mt < 4; mt++)
      #pragma unroll
      for (int j = 0; j < 4; j++){
        int p = mt*16 + quad*4 + j;
        int ta = p>>3, tb = p&7;
        int sa = 2*ta + pa, sb = 2*tb + pb;
        smem[((sa+1)*18 + (sb+1))*32 + o] = f2bf(fmaxf((acc[nt][mt][j]-m1)*rs1, 0.f));
      }
  }
  __syncthreads();
  f32x4 acc2[16] = {z,z,z,z,z,z,z,z,z,z,z,z,z,z,z,z};
  #pragma unroll
  for (int ks = 0; ks < 4; ks++){
    int da = ks & 1, db = ks >> 1;
    #pragma unroll
    for (int mt = 0; mt < 16; mt++){
      int p = mt*16 + ln;
      int ta = p>>4, tb = p&15;
      bf16x8 a = *(const bf16x8*)&smem[((ta+da+pa)*18 + (tb+db+pb))*32 + quad*8];
      acc2[mt] = __builtin_amdgcn_mfma_f32_16x16x32_bf16(a, bfr2[ks], acc2[mt],0,0,0);
    }
  }
  s = 0.f; s2 = 0.f;
  float bz2 = bias2[ln];
  #pragma unroll
  for (int mt = 0; mt < 16; mt++)
    #pragma unroll
    for (int j = 0; j < 4; j++){
      float v = acc2[mt][j] + bz2;
      acc2[mt][j] = v; s += v; s2 += v*v;
    }
  block_reduce2(s, s2, sbuf);
  float m = s*(1.f/16384.f);
  float rs = rsqrtf(s2*(1.f/16384.f) - m*m + 1e-5f);
  short* op = outp + (size_t)n*16384;
  #pragma unroll
  for (int mt = 0; mt < 16; mt++)
    #pragma unroll
    for (int j = 0; j < 4; j++){
      int p = mt*16 + quad*4 + j;
      int ta = p>>4, tb = p&15;
      op[(2*ta+pa)*512 + (2*tb+pb)*16 + ln] = f2bf(fmaxf((acc2[mt][j]-m)*rs, 0.f));
    }
}

// ---------------- dec_conv3 (final bf16 in) ----------------
__global__ __launch_bounds__(256) void dec_conv3_ig(
    const short* __restrict__ in, const float* __restrict__ CWT, const float* __restrict__ bias,
    float* __restrict__ outp)
{
  __shared__ __align__(16) float in_t[9792];   // [sa34][sb18][i16]
  __shared__ __align__(16) float wl[256];
  int bx = blockIdx.x;
  int n = bx >> 1, b0 = (bx & 1) * 32, tb0 = b0 >> 1;
  int tid = threadIdx.x;
  const short* ip = in + (size_t)n*16384;
  for (int l = tid; l < 9792; l += 256){
    int i = l & 15, sb = (l >> 4) % 18, sap = l / 288;
    int sa = sap - 1, sbg = tb0 - 1 + sb;
    float v = 0.f;
    if ((unsigned)sa < 32u && (unsigned)sbg < 32u)
      v = bf2f(ip[sa*512 + sbg*16 + i]);
    in_t[(sap*18 + sb)*16 + i] = v;
  }
  for (int l = tid; l < 256; l += 256) wl[l] = CWT[l];
  __syncthreads();
  float bv = bias[0];
  int bl = tid & 31, ath = tid >> 5;
  int b = b0 + bl;
  int tb = b >> 1, pb = b & 1;
  float* op = outp + (size_t)n*4096;
  #pragma unroll
  for (int j = 0; j < 8; j++){
    int a = ath*8 + j;
    int ta = a >> 1, pa = a & 1;
    float4 s4 = make_float4(0.f,0.f,0.f,0.f);
    #pragma unroll
    for (int db = 0; db < 2; db++){
      int sb = tb + db + (pb ? 0 : -1);
      int sbl = sb - (tb0 - 1);
      #pragma unroll
      for (int da = 0; da < 2; da++){
        int sa = ta + da + (pa ? 0 : -1);
        int sap = sa + 1;
        const float4* A4 = (const float4*)&in_t[(sap*18 + sbl)*16];
        const float4* B4 = (const float4*)&wl[((pb*2+pa)*4 + db*2+da)*16];
        #pragma unroll
        for (int q = 0; q < 4; q++){
          float4 av = A4[q], bw = B4[q];
          s4.x += av.x*bw.x; s4.y += av.y*bw.y;
          s4.z += av.z*bw.z; s4.w += av.w*bw.w;
        }
      }
    }
    op[a*64 + b] = sigf(bv + s4.x + s4.y + s4.z + s4.w);
  }
}

extern "C" void kernel_launch(void* const* d_in, const int* in_sizes, int n_in,
                              void* d_out, int out_size, void* d_ws, size_t ws_size,
                              hipStream_t stream) {
  const float* x      = (const float*)d_in[0];
  const float* state  = (const float*)d_in[1];
  const float* c1w    = (const float*)d_in[2];
  const float* c1b    = (const float*)d_in[3];
  const float* c2w    = (const float*)d_in[4];
  const float* c2b    = (const float*)d_in[5];
  const float* c3w    = (const float*)d_in[6];
  const float* c3b    = (const float*)d_in[7];
  const float* efc_w  = (const float*)d_in[8];
  const float* efc_b  = (const float*)d_in[9];
  const float* renc_w = (const float*)d_in[10];
  const float* renc_b = (const float*)d_in[11];
  const float* core_w = (const float*)d_in[12];
  const float* core_b = (const float*)d_in[13];
  const float* ctx_w  = (const float*)d_in[14];
  const float* ctx_b  = (const float*)d_in[15];
  const float* att1_w = (const float*)d_in[16];
  const float* att1_b = (const float*)d_in[17];
  const float* att2_w = (const float*)d_in[18];
  const float* att2_b = (const float*)d_in[19];
  const float* out_w  = (const float*)d_in[20];
  const float* out_b  = (const float*)d_in[21];
  const float* dfc1_w = (const float*)d_in[22];
  const float* dfc1_b = (const float*)d_in[23];
  const float* dfc2_w = (const float*)d_in[24];
  const float* dfc2_b = (const float*)d_in[25];
  const float* d1w    = (const float*)d_in[26];
  const float* d1b    = (const float*)d_in[27];
  const float* d2w    = (const float*)d_in[28];
  const float* d2b    = (const float*)d_in[29];
  const float* d3w    = (const float*)d_in[30];
  const float* d3b    = (const float*)d_in[31];

  float* wsf = (float*)d_ws;
  size_t o = 0;
  float* PB   = wsf + o; o += (size_t)1600*1024;    // split-K partials (fp32)
  float* PB2  = wsf + o; o += (size_t)2688*100*4;   // att1 partials (KS=4)
  float* CWT3 = wsf + o; o += 256;
  // bf16 buffers (sizes in shorts; offsets in floats)
  short* E1b  = (short*)(wsf + o); o += (size_t)384*16384/2;   // enc1 final; later dec2 final
  short* E2b  = (short*)(wsf + o); o += (size_t)384*8192/2;    // (unused after fusion)
  short* E3b  = (short*)(wsf + o); o += (size_t)384*4096/2;    // enc3 final; later G2 final
  short* TOTb = (short*)(wsf + o); o += (size_t)384*1024/2;    // [s1|pad|eff|pad|h]
  short* C1b  = (short*)(wsf + o); o += (size_t)2688*256/2;
  short* XRb  = (short*)(wsf + o); o += (size_t)384*256/2;
  short* G1b  = (short*)(wsf + o); o += (size_t)384*512/2;
  short* SBF  = (short*)(wsf + o); o += (size_t)384*256/2;
  short* BtC2 = (short*)(wsf + o); o += 8192/2;
  short* BtC3 = (short*)(wsf + o); o += 32768/2;
  short* BD1  = (short*)(wsf + o); o += 32768/2;
  short* BD2  = (short*)(wsf + o); o += 8192/2;
  short* BT_efc  = (short*)(wsf + o); o += 2097152/2;
  short* BT_renc = (short*)(wsf + o); o += 64000/2;
  short* BT_core = (short*)(wsf + o); o += 128000/2;
  short* BT_ctx  = (short*)(wsf + o); o += 64000/2;
  short* BT_att1 = (short*)(wsf + o); o += 25600/2;
  short* BT_out  = (short*)(wsf + o); o += 256000/2;
  short* BT_dfc1 = (short*)(wsf + o); o += 131072/2;
  short* BT_dfc2 = (short*)(wsf + o); o += 2097152/2;
  short* D2b = E1b;
  short* G2b = E3b;
  (void)E2b;

  float* xout = (float*)d_out;
  float* sout = xout + (size_t)384*4096;

  // one prep kernel: weight transposes + folds + state cvt + TOT pad zero
  prep_combined<<<1448, 256, 0, stream>>>(
      efc_w, BT_efc, dfc2_w, BT_dfc2, out_w, BT_out, core_w, BT_core,
      dfc1_w, BT_dfc1, renc_w, BT_renc, ctx_w, BT_ctx, att1_w, BT_att1,
      d3w, CWT3, c2w, BtC2, c3w, BtC3, d1w, BD1, d2w, BD2, state, SBF, TOTb);

  // encoder (conv1 then fused conv2+3; final activated bf16 chain)
  enc_conv1_ig<<<384, 256, 0, stream>>>(x, c1w, c1b, E1b);
  enc_conv23_mfma<<<384, 256, 0, stream>>>(E1b, BtC2, c2b, BtC3, c3b, E3b);
  gemm_mfma<<<dim3(8,6,8), 256, 0, stream>>>(E3b, BT_efc, PB, 384, 512, 4096, 512);
  reduce_ln<<<384, 256, 0, stream>>>(PB, efc_b, TOTb+512, 384, 512, 8, 1024, 2, 1);

  // state path
  gemm_mfma<<<dim3(4,6,8), 256, 0, stream>>>(SBF, BT_renc, PB, 384, 250, 256, 32);
  reduce_ln<<<384, 256, 0, stream>>>(PB, renc_b, TOTb, 384, 250, 8, 1024, 1, 1);
  gemm_core_mfma<<<dim3(4,42,2), 256, 0, stream>>>(TOTb, BT_core, PB, 2688, 250, 256);
  reduce_ln<<<2688, 256, 0, stream>>>(PB, core_b, C1b, 2688, 250, 2, 256, 1, 1);
  gemm_mfma<<<dim3(4,42,2), 256, 0, stream>>>(C1b, BT_ctx, PB, 2688, 250, 256, 128);
  gemm_mfma<<<dim3(2,42,4), 256, 0, stream>>>(C1b, BT_att1, PB2, 2688, 100, 256, 64);
  ctx_att_effect<<<384, 448, 0, stream>>>(PB, ctx_b, PB2, att1_b, att2_w, att2_b, TOTb);

  // combine
  gemm_mfma<<<dim3(4,6,8), 256, 0, stream>>>(TOTb, BT_out, PB, 384, 250, 1024, 128);
  reduce_ns<<<384, 256, 0, stream>>>(PB, out_b, XRb, sout, 384, 250, 8);

  // decoder FC
  gemm_mfma<<<dim3(8,6,4), 256, 0, stream>>>(XRb, BT_dfc1, PB, 384, 512, 256, 64);
  reduce_ln<<<384, 256, 0, stream>>>(PB, dfc1_b, G1b, 384, 512, 4, 512, 1, 1);
  gemm_mfma<<<dim3(64,6,1), 256, 0, stream>>>(G1b, BT_dfc2, PB, 384, 4096, 512, 512);
  reduce_ln<<<384, 256, 0, stream>>>(PB, dfc2_b, G2b, 384, 4096, 1, 4096, 1, 1);

  // decoder convs (fused conv1+2, then conv3)
  dec_conv12_mfma<<<384, 256, 0, stream>>>(G2b, BD1, d1b, BD2, d2b, D2b);
  dec_conv3_ig<<<768, 256, 0, stream>>>(D2b, CWT3, d3b, xout);

  (void)in_sizes; (void)n_in; (void)out_size; (void)ws_size;
}